// Round 10
// baseline (390.851 us; speedup 1.0000x reference)
//
#include <hip/hip_runtime.h>
#include <math.h>

#define Bn   4
#define Tn   2048
#define Dn   1024
#define Hn   4
#define DKn  128
#define DVn  256
#define KDn  512
#define VDn  1024
#define NROWS 8192
#define NCC  16
#define CLO  128
#define LOG_T_REF_F 6.2383246250395075f

using bf16x8 = __attribute__((ext_vector_type(8))) short;
using f32x4  = __attribute__((ext_vector_type(4))) float;
using f32x2  = __attribute__((ext_vector_type(2))) float;

__device__ __forceinline__ float softplus_f(float x) {
    return fmaxf(x, 0.0f) + log1pf(expf(-fabsf(x)));
}
__device__ __forceinline__ ushort f2bf(float f) {
    unsigned u = __float_as_uint(f);
    u = (u + 0x7fffu + ((u >> 16) & 1u)) >> 16;
    return (ushort)u;
}
__device__ __forceinline__ void gload16(const void* g, void* l) {
    __builtin_amdgcn_global_load_lds(
        (const __attribute__((address_space(1))) unsigned*)g,
        (__attribute__((address_space(3))) unsigned*)l, 16, 0, 0);
}
// packed fp32 (CDNA VOP3P, 2x rate): in-place forms to avoid extra movs
__device__ __forceinline__ void pk_mul_ip(f32x2& a, f32x2 b) {   // a *= b
    asm("v_pk_mul_f32 %0, %0, %1" : "+v"(a) : "v"(b));
}
__device__ __forceinline__ void pk_fma_ip(f32x2& acc, f32x2 a, f32x2 b) { // acc += a*b
    asm("v_pk_fma_f32 %0, %1, %2, %0" : "+v"(acc) : "v"(a), "v"(b));
}
// packed full-sum butterfly over each aligned 16-lane group, pure VALU (DPP)
__device__ __forceinline__ f32x2 dpp_red16_x2(f32x2 p) {
    f32x2 t;
#define RSTEP(ctl)                                                                              \
    t.x = __int_as_float(__builtin_amdgcn_mov_dpp(__float_as_int(p.x), ctl, 0xF, 0xF, true));   \
    t.y = __int_as_float(__builtin_amdgcn_mov_dpp(__float_as_int(p.y), ctl, 0xF, 0xF, true));   \
    p = p + t;
    RSTEP(0xB1)   // quad_perm xor1
    RSTEP(0x4E)   // quad_perm xor2
    RSTEP(0x124)  // row_ror:4
    RSTEP(0x128)  // row_ror:8
#undef RSTEP
    return p;
}

// ---------- cast fp32 -> bf16 ----------
__global__ __launch_bounds__(256) void cast_f2b(const float* __restrict__ x,
                                                ushort* __restrict__ y, int n4) {
    int i = blockIdx.x * 256 + threadIdx.x;
    if (i < n4) {
        float4 v = *(const float4*)&x[i * 4];
        ushort4 o;
        o.x = f2bf(v.x); o.y = f2bf(v.y); o.z = f2bf(v.z); o.w = f2bf(v.w);
        *(ushort4*)&y[i * 4] = o;
    }
}

// ---------- bf16 MFMA GEMM (unchanged from R9) ----------
template<int MODE, int NX>
__global__ __launch_bounds__(256) void mm2(const ushort* __restrict__ A,
    const ushort* __restrict__ Bw, float* __restrict__ C,
    ushort* __restrict__ C2, float* __restrict__ Eo,
    const float* __restrict__ dt_bias, const float* __restrict__ A_log_base,
    const float* __restrict__ A_log_delta)
{
    __shared__ __align__(16) ushort As[4][128][8];
    __shared__ __align__(16) ushort Bs[4][128][8];
    const int raw = blockIdx.x;
    const int nwg = NX * 64;
    const int l = (raw & 7) * (nwg >> 3) + (raw >> 3);
    const int bx = l % NX, by = l / NX;
    const int tid = threadIdx.x;
    const int lane = tid & 63, w = tid >> 6;
    const int l15 = lane & 15, lg = lane >> 4;
    const int wr = (w >> 1) << 6, wc = (w & 1) << 6;
    const int row0 = by << 7, col0 = bx << 7;

    const ushort* Ag0 = A  + (size_t)(row0 + lane) * Dn + w * 8;
    const ushort* Ag1 = A  + (size_t)(row0 + 64 + lane) * Dn + w * 8;
    const ushort* Bg0 = Bw + (size_t)(col0 + lane) * Dn + w * 8;
    const ushort* Bg1 = Bw + (size_t)(col0 + 64 + lane) * Dn + w * 8;
    ushort* lA0 = &As[w][0][0];
    ushort* lA1 = &As[w][64][0];
    ushort* lB0 = &Bs[w][0][0];
    ushort* lB1 = &Bs[w][64][0];

    f32x4 acc[4][4];
    #pragma unroll
    for (int m = 0; m < 4; ++m)
        #pragma unroll
        for (int n = 0; n < 4; ++n)
            acc[m][n] = (f32x4){0.f, 0.f, 0.f, 0.f};

    for (int kt = 0; kt < Dn; kt += 32) {
        __syncthreads();
        gload16(Ag0 + kt, lA0);
        gload16(Ag1 + kt, lA1);
        gload16(Bg0 + kt, lB0);
        gload16(Bg1 + kt, lB1);
        __syncthreads();
        bf16x8 af[4], bv[4];
        #pragma unroll
        for (int m = 0; m < 4; ++m) af[m] = *(const bf16x8*)&As[lg][wr + m*16 + l15][0];
        #pragma unroll
        for (int n = 0; n < 4; ++n) bv[n] = *(const bf16x8*)&Bs[lg][wc + n*16 + l15][0];
        #pragma unroll
        for (int m = 0; m < 4; ++m)
            #pragma unroll
            for (int n = 0; n < 4; ++n)
                acc[m][n] = __builtin_amdgcn_mfma_f32_16x16x32_bf16(af[m], bv[n], acc[m][n], 0, 0, 0);
    }

    if (MODE == 1 && col0 >= 1024) {
        const float base_ = A_log_base[0];
        const float s0 = softplus_f(A_log_delta[0]);
        const float s1 = softplus_f(A_log_delta[1]);
        const float s2 = softplus_f(A_log_delta[2]);
        const float c3 = s0 + s1 + s2;
        const float mg = c3 * (1.0f / 3.0f);
        float pf[4][4];
        #pragma unroll
        for (int m = 0; m < 4; ++m) {
            const int row = row0 + wr + m * 16 + lg * 4;
            #pragma unroll
            for (int r = 0; r < 4; ++r) {
                const int t = (row + r) & (Tn - 1);
                pf[m][r] = logf((float)(t + 1));
            }
        }
        #pragma unroll
        for (int n = 0; n < 4; ++n) {
            const int dk = col0 - 1024 + wc + n * 16 + l15;
            const int h = dk >> 7;
            const float cumh = (h == 0) ? 0.f : (h == 1) ? s0 : (h == 2) ? s0 + s1 : c3;
            float alpha = (float)(3 - h) * (1.0f / 3.0f)
                        + (cumh - (float)h * mg) * (1.0f / LOG_T_REF_F);
            alpha = fminf(fmaxf(alpha, 0.0f), 1.0f);
            const float expA = expf(base_ + cumh);
            const float db = dt_bias[dk];
            #pragma unroll
            for (int m = 0; m < 4; ++m) {
                const int row = row0 + wr + m * 16 + lg * 4;
                #pragma unroll
                for (int r = 0; r < 4; ++r) {
                    const float p = expf(-alpha * pf[m][r]);
                    Eo[(size_t)(row + r) * KDn + dk] =
                        expf(-expA * softplus_f(acc[m][n][r] + db) * p);
                }
            }
        }
    } else if (MODE == 2 && col0 >= 1024) {
        #pragma unroll
        for (int m = 0; m < 4; ++m) {
            const int row = row0 + wr + m * 16 + lg * 4;
            #pragma unroll
            for (int n = 0; n < 4; ++n) {
                const int col = col0 - 1024 + wc + n * 16 + l15;
                #pragma unroll
                for (int r = 0; r < 4; ++r)
                    C2[(size_t)(row + r) * 1024 + col] = f2bf(acc[m][n][r]);
            }
        }
    } else {
        const float s = (MODE == 1 && col0 < 512) ? 0.08838834764831845f : 1.0f;
        #pragma unroll
        for (int m = 0; m < 4; ++m) {
            const int row = row0 + wr + m * 16 + lg * 4;
            #pragma unroll
            for (int n = 0; n < 4; ++n) {
                const int col = col0 + wc + n * 16 + l15;
                #pragma unroll
                for (int r = 0; r < 4; ++r)
                    C[(size_t)(row + r) * 1024 + col] = acc[m][n][r] * s;
            }
        }
    }
}

// ---------- single-pass chunked GLA scan (LDS-staged, dv=8/thread, pk-fp32) ----------
// Grid 512 = 16co x 16bh x 2dvb, XCD-swizzled. Thread (part=tid&15, dvi=tid>>4):
// dk pairs {p4,p4+1},{p4+2,p4+3},{64+p4,+1},{64+p4+2,+3}; dv = dvb*128 + dvi*8.
// Writes o_local, S_local[co], Dc, q~ = q * Lam.
__global__ __launch_bounds__(256, 2) void gla_scan(const float* __restrict__ qk,
    const float* __restrict__ E, const float* __restrict__ vb,
    float* __restrict__ o, float* __restrict__ Sl, float* __restrict__ qt,
    float* __restrict__ Dc)
{
    __shared__ __align__(16) float sb[8192];  // lq | lk | lE | lv, each [16][128]
    float* lq = sb;
    float* lk = sb + 2048;
    float* lE = sb + 4096;
    float* lv = sb + 6144;

    const int raw = blockIdx.x;
    const int l = (raw & 7) * 64 + (raw >> 3);
    const int dvb = l & 1, bh = (l >> 1) & 15, co = l >> 5;  // co: 0..15
    const int tid = threadIdx.x;
    const int part = tid & 15, dvi = tid >> 4;
    const int w = tid >> 6;
    const int b = bh >> 2, h = bh & 3;
    const int t0 = co * CLO;
    const int dvl = dvi * 8;                  // 0..120 within 128-slice
    const int dv = dvb * 128 + dvl;

    // staging: all four tiles are [16][128]; thread covers float4 #tid and #tid+256
    const int grow = tid >> 5;                // rows 0..7 (call 1), +8 (call 2)
    const int gcol = (tid & 31) << 2;
    int oq = (b * Tn + t0 + grow) * 1024 + h * DKn + gcol;
    int okk = oq + 512;
    int oe = (b * Tn + t0 + grow) * 512 + h * DKn + gcol;
    int ov = (b * Tn + t0 + grow) * 1024 + h * DVn + dvb * 128 + gcol;
    float* dq = lq + w * 256;
    float* dkk = lk + w * 256;
    float* de = lE + w * 256;
    float* dvv = lv + w * 256;

    f32x2 S[4][8], Lam[4];
    #pragma unroll
    for (int i = 0; i < 4; ++i) {
        Lam[i] = (f32x2){1.f, 1.f};
        #pragma unroll
        for (int j = 0; j < 8; ++j) S[i][j] = (f32x2){0.f, 0.f};
    }

    int oo  = (b * Tn + t0) * 1024 + h * DVn + dv;
    int qo2 = (b * Tn + t0) * 512 + h * DKn + part * 4;

    for (int tile = 0; tile < CLO / 16; ++tile) {
        __syncthreads();
        gload16(qk + oq,          dq);
        gload16(qk + oq + 8192,   dq + 1024);
        gload16(qk + okk,         dkk);
        gload16(qk + okk + 8192,  dkk + 1024);
        gload16(E + oe,           de);
        gload16(E + oe + 4096,    de + 1024);
        gload16(vb + ov,          dvv);
        gload16(vb + ov + 8192,   dvv + 1024);
        oq += 16 * 1024; okk += 16 * 1024; oe += 16 * 512; ov += 16 * 1024;
        __syncthreads();

        #pragma unroll
        for (int tt = 0; tt < 16; ++tt) {
            float4 qA = *(const float4*)&lq[tt * 128 + part * 4];
            float4 qB = *(const float4*)&lq[tt * 128 + 64 + part * 4];
            float4 kA = *(const float4*)&lk[tt * 128 + part * 4];
            float4 kB = *(const float4*)&lk[tt * 128 + 64 + part * 4];
            float4 eA = *(const float4*)&lE[tt * 128 + part * 4];
            float4 eB = *(const float4*)&lE[tt * 128 + 64 + part * 4];
            float4 v0 = *(const float4*)&lv[tt * 128 + dvl];
            float4 v1 = *(const float4*)&lv[tt * 128 + dvl + 4];
            f32x2 q2[4] = {{qA.x,qA.y},{qA.z,qA.w},{qB.x,qB.y},{qB.z,qB.w}};
            f32x2 k2[4] = {{kA.x,kA.y},{kA.z,kA.w},{kB.x,kB.y},{kB.z,kB.w}};
            f32x2 e2[4] = {{eA.x,eA.y},{eA.z,eA.w},{eB.x,eB.y},{eB.z,eB.w}};
            const f32x2 vs[8] = {{v0.x,v0.x},{v0.y,v0.y},{v0.z,v0.z},{v0.w,v0.w},
                                 {v1.x,v1.x},{v1.y,v1.y},{v1.z,v1.z},{v1.w,v1.w}};
            f32x2 p[8] = {{0.f,0.f},{0.f,0.f},{0.f,0.f},{0.f,0.f},
                          {0.f,0.f},{0.f,0.f},{0.f,0.f},{0.f,0.f}};
            #pragma unroll
            for (int i = 0; i < 4; ++i) {
                pk_mul_ip(Lam[i], e2[i]);
                #pragma unroll
                for (int j = 0; j < 8; ++j) {
                    pk_mul_ip(S[i][j], e2[i]);          // S *= e
                    pk_fma_ip(S[i][j], k2[i], vs[j]);   // S += k*v
                    pk_fma_ip(p[j], q2[i], S[i][j]);    // p += q*S
                }
            }
            f32x2 pp0 = (f32x2){p[0].x + p[0].y, p[1].x + p[1].y};
            f32x2 pp1 = (f32x2){p[2].x + p[2].y, p[3].x + p[3].y};
            f32x2 pp2 = (f32x2){p[4].x + p[4].y, p[5].x + p[5].y};
            f32x2 pp3 = (f32x2){p[6].x + p[6].y, p[7].x + p[7].y};
            pp0 = dpp_red16_x2(pp0);
            pp1 = dpp_red16_x2(pp1);
            pp2 = dpp_red16_x2(pp2);
            pp3 = dpp_red16_x2(pp3);
            if (part == 0) {
                *(float4*)(o + oo)     = make_float4(pp0.x, pp0.y, pp1.x, pp1.y);
                *(float4*)(o + oo + 4) = make_float4(pp2.x, pp2.y, pp3.x, pp3.y);
            }
            oo += 1024;
            if (dvb == 0 && tid < 16) {  // q~ = q * Lam (one writer per dk)
                f32x2 a0 = q2[0] * Lam[0], a1 = q2[1] * Lam[1];
                f32x2 a2 = q2[2] * Lam[2], a3 = q2[3] * Lam[3];
                *(float4*)(qt + qo2)      = make_float4(a0.x, a0.y, a1.x, a1.y);
                *(float4*)(qt + qo2 + 64) = make_float4(a2.x, a2.y, a3.x, a3.y);
            }
            qo2 += 512;
        }
    }

    // local end-state writeback
    float* sp = Sl + (((size_t)co * 16 + bh) << 15) + dv;
    #pragma unroll
    for (int i = 0; i < 4; ++i) {
        const int dke = (i < 2) ? part * 4 + i * 2 : 64 + part * 4 + (i - 2) * 2;
        *(float4*)&sp[(size_t)(dke + 0) * DVn] =
            make_float4(S[i][0].x, S[i][1].x, S[i][2].x, S[i][3].x);
        *(float4*)&sp[(size_t)(dke + 0) * DVn + 4] =
            make_float4(S[i][4].x, S[i][5].x, S[i][6].x, S[i][7].x);
        *(float4*)&sp[(size_t)(dke + 1) * DVn] =
            make_float4(S[i][0].y, S[i][1].y, S[i][2].y, S[i][3].y);
        *(float4*)&sp[(size_t)(dke + 1) * DVn + 4] =
            make_float4(S[i][4].y, S[i][5].y, S[i][6].y, S[i][7].y);
    }
    if (dvb == 0 && dvi == 0) {
        float* dp = Dc + (co * 16 + bh) * DKn;
        #pragma unroll
        for (int i = 0; i < 4; ++i) {
            const int dke = (i < 2) ? part * 4 + i * 2 : 64 + part * 4 + (i - 2) * 2;
            *(float2*)&dp[dke] = make_float2(Lam[i].x, Lam[i].y);
        }
    }
}

// sequential chunk combine (16 coarse chunks): overwrite Sl[c] with START state
__global__ __launch_bounds__(256) void combine(float* __restrict__ Sl,
                                               const float* __restrict__ Dc) {
    const int bh = blockIdx.y;
    const int e4 = blockIdx.x * 256 + threadIdx.x;
    const int dk = e4 >> 6;
    float4 s = make_float4(0.f, 0.f, 0.f, 0.f);
    #pragma unroll 4
    for (int c = 0; c < NCC; ++c) {
        float4* p = (float4*)(Sl + (((size_t)c * 16 + bh) << 15)) + e4;
        float4 local = *p;
        const float d = Dc[(c * 16 + bh) * DKn + dk];
        *p = s;
        s.x = s.x * d + local.x;  s.y = s.y * d + local.y;
        s.z = s.z * d + local.z;  s.w = s.w * d + local.w;
    }
}

// inter-chunk correction: o[t][dv] += sum_dk q~[t][dk] * S_start[dk][dv]
__global__ __launch_bounds__(256, 4) void fixup(const float* __restrict__ qt,
    const float* __restrict__ Sl, float* __restrict__ o)
{
    __shared__ __align__(16) float Aq[16][128];  // [kk][t]
    __shared__ __align__(16) float Bs[16][64];   // [kk][dv]
    const int raw = blockIdx.x;
    const int l = (raw & 7) * 128 + (raw >> 3);
    const int dvt = l & 3, bh = (l >> 2) & 15, co = l >> 6;
    const int b = bh >> 2, h = bh & 3;
    const int tid = threadIdx.x;
    const int tx = tid & 15, ty = tid >> 4;
    const int t0 = co * CLO;
    const int dv0 = dvt * 64;

    const float* qbase = qt + (size_t)(b * Tn + t0) * 512 + h * DKn;
    const float* sbase = Sl + (((size_t)co * 16 + bh) << 15) + dv0;

    float acc[8][4] = {};
    for (int k0 = 0; k0 < DKn; k0 += 16) {
        __syncthreads();
        #pragma unroll
        for (int s = 0; s < 2; ++s) {
            const int f = tid + s * 256;
            const int t = f >> 2, kk4 = (f & 3) << 2;
            float4 a = *(const float4*)&qbase[(size_t)t * 512 + k0 + kk4];
            Aq[kk4 + 0][t] = a.x; Aq[kk4 + 1][t] = a.y;
            Aq[kk4 + 2][t] = a.z; Aq[kk4 + 3][t] = a.w;
        }
        {
            const int dk = tid >> 4, dvq = (tid & 15) << 2;
            *(float4*)&Bs[dk][dvq] = *(const float4*)&sbase[(size_t)(k0 + dk) * DVn + dvq];
        }
        __syncthreads();
        #pragma unroll
        for (int kk = 0; kk < 16; ++kk) {
            float4 a0 = *(const float4*)&Aq[kk][ty * 8];
            float4 a1 = *(const float4*)&Aq[kk][ty * 8 + 4];
            float4 bv = *(const float4*)&Bs[kk][tx * 4];
            float ar[8] = {a0.x,a0.y,a0.z,a0.w,a1.x,a1.y,a1.z,a1.w};
            float br[4] = {bv.x,bv.y,bv.z,bv.w};
            #pragma unroll
            for (int i = 0; i < 8; ++i)
                #pragma unroll
                for (int j = 0; j < 4; ++j)
                    acc[i][j] += ar[i] * br[j];
        }
    }
    float* ob = o + (size_t)(b * Tn + t0) * 1024 + h * DVn + dv0;
    #pragma unroll
    for (int i = 0; i < 8; ++i) {
        float* row = ob + (size_t)(ty * 8 + i) * 1024 + tx * 4;
        float4 c = *(float4*)row;
        c.x += acc[i][0]; c.y += acc[i][1];
        c.z += acc[i][2]; c.w += acc[i][3];
        *(float4*)row = c;
    }
}

// ---------- RMSNorm + swish gate (g in bf16) -> bf16 ----------
__global__ __launch_bounds__(256) void rms_gate(const float* __restrict__ o,
    const ushort* __restrict__ gbf, const float* __restrict__ wt,
    ushort* __restrict__ obf)
{
    const int tid = threadIdx.x;
    const int w = tid >> 6, lane = tid & 63;
    const int row = blockIdx.x * 4 + w;
    const int n = row >> 2, h = row & 3;
    const size_t ob_base = (size_t)n * VDn + h * DVn + lane * 4;

    float4 o4 = *(const float4*)&o[ob_base];
    float ss = o4.x*o4.x + o4.y*o4.y + o4.z*o4.z + o4.w*o4.w;
    #pragma unroll
    for (int m = 1; m < 64; m <<= 1) ss += __shfl_xor(ss, m);
    const float r = rsqrtf(ss * (1.0f / DVn) + 1e-5f);

    ushort4 gu = *(const ushort4*)&gbf[ob_base];
    float gx = __uint_as_float((unsigned)gu.x << 16);
    float gy = __uint_as_float((unsigned)gu.y << 16);
    float gz = __uint_as_float((unsigned)gu.z << 16);
    float gw = __uint_as_float((unsigned)gu.w << 16);
    float4 w4 = *(const float4*)&wt[h * DVn + lane * 4];
    ushort4 u;
    u.x = f2bf(o4.x * r * w4.x * (gx / (1.0f + expf(-gx))));
    u.y = f2bf(o4.y * r * w4.y * (gy / (1.0f + expf(-gy))));
    u.z = f2bf(o4.z * r * w4.z * (gz / (1.0f + expf(-gz))));
    u.w = f2bf(o4.w * r * w4.w * (gw / (1.0f + expf(-gw))));
    *(ushort4*)&obf[ob_base] = u;
}

extern "C" void kernel_launch(void* const* d_in, const int* in_sizes, int n_in,
                              void* d_out, int out_size, void* d_ws, size_t ws_size,
                              hipStream_t stream) {
    const float* hs          = (const float*)d_in[0];
    const float* Wq          = (const float*)d_in[1];
    const float* Wk          = (const float*)d_in[2];
    const float* Wv          = (const float*)d_in[3];
    const float* Wg          = (const float*)d_in[4];
    const float* Wa          = (const float*)d_in[5];
    const float* Wo          = (const float*)d_in[6];
    const float* A_log_base  = (const float*)d_in[7];
    const float* A_log_delta = (const float*)d_in[8];
    const float* dt_bias     = (const float*)d_in[9];
    const float* gnw         = (const float*)d_in[10];
    float* out = (float*)d_out;

    char* ws = (char*)d_ws;
    float*  qk   = (float*)(ws);                           // 32MB [8192][1024] q|k
    float*  vb   = (float*)(ws + ((size_t)32  << 20));     // 32MB [8192][1024] v
    float*  Eb   = (float*)(ws + ((size_t)64  << 20));     // 16MB [8192][512]
    float*  Sl   = (float*)(ws + ((size_t)80  << 20));     // 32MB [16][16][128][256]
    float*  qtb  = (float*)(ws + ((size_t)112 << 20));     // 16MB [8192][512] q~
    float*  ob   = (float*)(ws + ((size_t)144 << 20));     // 32MB [8192][1024]
    ushort* hsb  = (ushort*)(ws + ((size_t)144 << 20));    // 16MB overlay on ob
    ushort* gbf  = (ushort*)(ws + ((size_t)176 << 20));    // 16MB [8192][1024] g bf16
    ushort* Wqkab= (ushort*)(ws + ((size_t)192 << 20));    //  3MB
    ushort* Wvgb = (ushort*)(ws + ((size_t)195 << 20));    //  4MB
    ushort* Wob  = (ushort*)(ws + ((size_t)199 << 20));    //  2MB
    float*  Dc   = (float*)(ws + ((size_t)201 << 20));     // 128KB [16][16][128]
    ushort* obf  = (ushort*)qk;                            // reuse qk after gla_scan

    // casts
    cast_f2b<<<NROWS * Dn / 4 / 256, 256, 0, stream>>>(hs, hsb, NROWS * Dn / 4);
    cast_f2b<<<512,  256, 0, stream>>>(Wq, Wqkab,              KDn * Dn / 4);
    cast_f2b<<<512,  256, 0, stream>>>(Wk, Wqkab + KDn * Dn,   KDn * Dn / 4);
    cast_f2b<<<512,  256, 0, stream>>>(Wa, Wqkab + 2*KDn * Dn, KDn * Dn / 4);
    cast_f2b<<<1024, 256, 0, stream>>>(Wv, Wvgb,               VDn * Dn / 4);
    cast_f2b<<<1024, 256, 0, stream>>>(Wg, Wvgb + VDn * Dn,    VDn * Dn / 4);
    cast_f2b<<<1024, 256, 0, stream>>>(Wo, Wob,                VDn * Dn / 4);

    // projections
    mm2<1,12><<<768,  256, 0, stream>>>(hsb, Wqkab, qk, nullptr, Eb,
                                        dt_bias, A_log_base, A_log_delta);
    mm2<2,16><<<1024, 256, 0, stream>>>(hsb, Wvgb, vb, gbf, nullptr,
                                        nullptr, nullptr, nullptr);

    // single-pass scan + coarse combine + inter-chunk fixup
    gla_scan<<<512, 256, 0, stream>>>(qk, Eb, vb, ob, Sl, qtb, Dc);
    combine<<<dim3(32, 16), 256, 0, stream>>>(Sl, Dc);
    fixup<<<1024, 256, 0, stream>>>(qtb, Sl, ob);

    // epilogue
    rms_gate<<<NROWS * Hn / 4, 256, 0, stream>>>(ob, gbf, gnw, obf);
    mm2<0,8><<<512, 256, 0, stream>>>(obf, Wob, out, nullptr, nullptr,
                                      nullptr, nullptr, nullptr);
}

// Round 11
// 377.387 us; speedup vs baseline: 1.0357x; 1.0357x over previous
//
#include <hip/hip_runtime.h>
#include <math.h>

#define Bn   4
#define Tn   2048
#define Dn   1024
#define Hn   4
#define DKn  128
#define DVn  256
#define KDn  512
#define VDn  1024
#define NROWS 8192
#define NCC  16
#define CLO  128
#define LOG_T_REF_F 6.2383246250395075f

using bf16x8 = __attribute__((ext_vector_type(8))) short;
using f32x4  = __attribute__((ext_vector_type(4))) float;
using f32x2  = __attribute__((ext_vector_type(2))) float;

__device__ __forceinline__ float softplus_f(float x) {
    return fmaxf(x, 0.0f) + log1pf(expf(-fabsf(x)));
}
__device__ __forceinline__ ushort f2bf(float f) {
    unsigned u = __float_as_uint(f);
    u = (u + 0x7fffu + ((u >> 16) & 1u)) >> 16;
    return (ushort)u;
}
__device__ __forceinline__ void gload16(const void* g, void* l) {
    __builtin_amdgcn_global_load_lds(
        (const __attribute__((address_space(1))) unsigned*)g,
        (__attribute__((address_space(3))) unsigned*)l, 16, 0, 0);
}
// packed fp32 (VOP3P, 2x rate)
__device__ __forceinline__ void pk_mul_ip(f32x2& a, f32x2 b) {   // a *= b
    asm("v_pk_mul_f32 %0, %0, %1" : "+v"(a) : "v"(b));
}
__device__ __forceinline__ void pk_fma_ip(f32x2& acc, f32x2 a, f32x2 b) { // acc += a*b
    asm("v_pk_fma_f32 %0, %1, %2, %0" : "+v"(acc) : "v"(a), "v"(b));
}
// acc += a * {b.lo, b.lo}  (op_sel broadcast of src1 low half)
__device__ __forceinline__ void pk_fma_bl(f32x2& acc, f32x2 a, f32x2 b) {
    asm("v_pk_fma_f32 %0, %1, %2, %0 op_sel:[0,0,0] op_sel_hi:[1,0,1]"
        : "+v"(acc) : "v"(a), "v"(b));
}
// acc += a * {b.hi, b.hi}
__device__ __forceinline__ void pk_fma_bh(f32x2& acc, f32x2 a, f32x2 b) {
    asm("v_pk_fma_f32 %0, %1, %2, %0 op_sel:[0,1,0] op_sel_hi:[1,1,1]"
        : "+v"(acc) : "v"(a), "v"(b));
}
// packed full-sum butterfly over each aligned 16-lane group, pure VALU (DPP)
__device__ __forceinline__ f32x2 dpp_red16_x2(f32x2 p) {
    f32x2 t;
#define RSTEP(ctl)                                                                              \
    t.x = __int_as_float(__builtin_amdgcn_mov_dpp(__float_as_int(p.x), ctl, 0xF, 0xF, true));   \
    t.y = __int_as_float(__builtin_amdgcn_mov_dpp(__float_as_int(p.y), ctl, 0xF, 0xF, true));   \
    p = p + t;
    RSTEP(0xB1)   // quad_perm xor1
    RSTEP(0x4E)   // quad_perm xor2
    RSTEP(0x124)  // row_ror:4
    RSTEP(0x128)  // row_ror:8
#undef RSTEP
    return p;
}

// ---------- fused fp32 -> bf16 cast over 7 segments ----------
struct CastArgs {
    const float* src[7];
    ushort* dst[7];
    int cum[8];           // cumulative float4 counts, cum[0] = 0
};
__global__ __launch_bounds__(256) void cast_all(CastArgs a) {
    const int total = a.cum[7];
    for (int i = blockIdx.x * 256 + threadIdx.x; i < total; i += gridDim.x * 256) {
        int s = 0;
        #pragma unroll
        for (int k = 1; k < 7; ++k) s += (i >= a.cum[k]) ? 1 : 0;
        const int off = i - a.cum[s];
        float4 v = *(const float4*)&a.src[s][(size_t)off * 4];
        ushort4 u;
        u.x = f2bf(v.x); u.y = f2bf(v.y); u.z = f2bf(v.z); u.w = f2bf(v.w);
        *(ushort4*)&a.dst[s][(size_t)off * 4] = u;
    }
}

// ---------- bf16 MFMA GEMM (unchanged from R10) ----------
template<int MODE, int NX>
__global__ __launch_bounds__(256) void mm2(const ushort* __restrict__ A,
    const ushort* __restrict__ Bw, float* __restrict__ C,
    ushort* __restrict__ C2, float* __restrict__ Eo,
    const float* __restrict__ dt_bias, const float* __restrict__ A_log_base,
    const float* __restrict__ A_log_delta)
{
    __shared__ __align__(16) ushort As[4][128][8];
    __shared__ __align__(16) ushort Bs[4][128][8];
    const int raw = blockIdx.x;
    const int nwg = NX * 64;
    const int l = (raw & 7) * (nwg >> 3) + (raw >> 3);
    const int bx = l % NX, by = l / NX;
    const int tid = threadIdx.x;
    const int lane = tid & 63, w = tid >> 6;
    const int l15 = lane & 15, lg = lane >> 4;
    const int wr = (w >> 1) << 6, wc = (w & 1) << 6;
    const int row0 = by << 7, col0 = bx << 7;

    const ushort* Ag0 = A  + (size_t)(row0 + lane) * Dn + w * 8;
    const ushort* Ag1 = A  + (size_t)(row0 + 64 + lane) * Dn + w * 8;
    const ushort* Bg0 = Bw + (size_t)(col0 + lane) * Dn + w * 8;
    const ushort* Bg1 = Bw + (size_t)(col0 + 64 + lane) * Dn + w * 8;
    ushort* lA0 = &As[w][0][0];
    ushort* lA1 = &As[w][64][0];
    ushort* lB0 = &Bs[w][0][0];
    ushort* lB1 = &Bs[w][64][0];

    f32x4 acc[4][4];
    #pragma unroll
    for (int m = 0; m < 4; ++m)
        #pragma unroll
        for (int n = 0; n < 4; ++n)
            acc[m][n] = (f32x4){0.f, 0.f, 0.f, 0.f};

    for (int kt = 0; kt < Dn; kt += 32) {
        __syncthreads();
        gload16(Ag0 + kt, lA0);
        gload16(Ag1 + kt, lA1);
        gload16(Bg0 + kt, lB0);
        gload16(Bg1 + kt, lB1);
        __syncthreads();
        bf16x8 af[4], bv[4];
        #pragma unroll
        for (int m = 0; m < 4; ++m) af[m] = *(const bf16x8*)&As[lg][wr + m*16 + l15][0];
        #pragma unroll
        for (int n = 0; n < 4; ++n) bv[n] = *(const bf16x8*)&Bs[lg][wc + n*16 + l15][0];
        #pragma unroll
        for (int m = 0; m < 4; ++m)
            #pragma unroll
            for (int n = 0; n < 4; ++n)
                acc[m][n] = __builtin_amdgcn_mfma_f32_16x16x32_bf16(af[m], bv[n], acc[m][n], 0, 0, 0);
    }

    if (MODE == 1 && col0 >= 1024) {
        const float base_ = A_log_base[0];
        const float s0 = softplus_f(A_log_delta[0]);
        const float s1 = softplus_f(A_log_delta[1]);
        const float s2 = softplus_f(A_log_delta[2]);
        const float c3 = s0 + s1 + s2;
        const float mg = c3 * (1.0f / 3.0f);
        float pf[4][4];
        #pragma unroll
        for (int m = 0; m < 4; ++m) {
            const int row = row0 + wr + m * 16 + lg * 4;
            #pragma unroll
            for (int r = 0; r < 4; ++r) {
                const int t = (row + r) & (Tn - 1);
                pf[m][r] = logf((float)(t + 1));
            }
        }
        #pragma unroll
        for (int n = 0; n < 4; ++n) {
            const int dk = col0 - 1024 + wc + n * 16 + l15;
            const int h = dk >> 7;
            const float cumh = (h == 0) ? 0.f : (h == 1) ? s0 : (h == 2) ? s0 + s1 : c3;
            float alpha = (float)(3 - h) * (1.0f / 3.0f)
                        + (cumh - (float)h * mg) * (1.0f / LOG_T_REF_F);
            alpha = fminf(fmaxf(alpha, 0.0f), 1.0f);
            const float expA = expf(base_ + cumh);
            const float db = dt_bias[dk];
            #pragma unroll
            for (int m = 0; m < 4; ++m) {
                const int row = row0 + wr + m * 16 + lg * 4;
                #pragma unroll
                for (int r = 0; r < 4; ++r) {
                    const float p = expf(-alpha * pf[m][r]);
                    Eo[(size_t)(row + r) * KDn + dk] =
                        expf(-expA * softplus_f(acc[m][n][r] + db) * p);
                }
            }
        }
    } else if (MODE == 2 && col0 >= 1024) {
        #pragma unroll
        for (int m = 0; m < 4; ++m) {
            const int row = row0 + wr + m * 16 + lg * 4;
            #pragma unroll
            for (int n = 0; n < 4; ++n) {
                const int col = col0 - 1024 + wc + n * 16 + l15;
                #pragma unroll
                for (int r = 0; r < 4; ++r)
                    C2[(size_t)(row + r) * 1024 + col] = f2bf(acc[m][n][r]);
            }
        }
    } else {
        const float s = (MODE == 1 && col0 < 512) ? 0.08838834764831845f : 1.0f;
        #pragma unroll
        for (int m = 0; m < 4; ++m) {
            const int row = row0 + wr + m * 16 + lg * 4;
            #pragma unroll
            for (int n = 0; n < 4; ++n) {
                const int col = col0 + wc + n * 16 + l15;
                #pragma unroll
                for (int r = 0; r < 4; ++r)
                    C[(size_t)(row + r) * 1024 + col] = acc[m][n][r] * s;
            }
        }
    }
}

// ---------- single-pass chunked GLA scan: LDS double-buffer + counted vmcnt ----------
// Grid 512 = 16co x 16bh x 2dvb, XCD-swizzled. Thread (part=tid&15, dvi=tid>>4):
// dk pairs {p4,p4+1},{p4+2,p4+3},{64+p4,+1},{64+p4+2,+3}; dv = dvb*128 + dvi*8.
// Writes o_local, S_local[co], Dc, q~ = q * Lam.
__global__ __launch_bounds__(256, 2) void gla_scan(const float* __restrict__ qk,
    const float* __restrict__ E, const float* __restrict__ vb,
    float* __restrict__ o, float* __restrict__ Sl, float* __restrict__ qt,
    float* __restrict__ Dc)
{
    __shared__ __align__(16) float sb[16384];  // 2 x (lq|lk|lE|lv), 32KB each

    const int raw = blockIdx.x;
    const int l = (raw & 7) * 64 + (raw >> 3);
    const int dvb = l & 1, bh = (l >> 1) & 15, co = l >> 5;  // co: 0..15
    const int tid = threadIdx.x;
    const int part = tid & 15, dvi = tid >> 4;
    const int w = tid >> 6;
    const int b = bh >> 2, h = bh & 3;
    const int t0 = co * CLO;
    const int dvl = dvi * 8;
    const int dv = dvb * 128 + dvl;

    const int grow = tid >> 5;
    const int gcol = (tid & 31) << 2;
    int oq = (b * Tn + t0 + grow) * 1024 + h * DKn + gcol;
    int okk = oq + 512;
    int oe = (b * Tn + t0 + grow) * 512 + h * DKn + gcol;
    int ov = (b * Tn + t0 + grow) * 1024 + h * DVn + dvb * 128 + gcol;
    const int woff = w * 256;

    f32x2 S[4][8], Lam[4], p[8];
    #pragma unroll
    for (int i = 0; i < 4; ++i) {
        Lam[i] = (f32x2){1.f, 1.f};
        #pragma unroll
        for (int j = 0; j < 8; ++j) S[i][j] = (f32x2){0.f, 0.f};
    }

    int oo  = (b * Tn + t0) * 1024 + h * DVn + dv;
    int qo2 = (b * Tn + t0) * 512 + h * DKn + part * 4;

    auto stage = [&](float* Bb) {
        gload16(qk + oq,         Bb + woff);
        gload16(qk + oq + 8192,  Bb + 1024 + woff);
        gload16(qk + okk,        Bb + 2048 + woff);
        gload16(qk + okk + 8192, Bb + 3072 + woff);
        gload16(E + oe,          Bb + 4096 + woff);
        gload16(E + oe + 4096,   Bb + 5120 + woff);
        gload16(vb + ov,         Bb + 6144 + woff);
        gload16(vb + ov + 8192,  Bb + 7168 + woff);
        oq += 16 * 1024; okk += 16 * 1024; oe += 16 * 512; ov += 16 * 1024;
    };

    stage(sb);   // prologue: tile 0 into buffer 0

    for (int tile = 0; tile < 8; ++tile) {
        const float* cb = sb + (tile & 1) * 8192;
        float* nb = sb + ((tile & 1) ^ 1) * 8192;
        if (tile < 7) {
            stage(nb);                                    // next tile in flight
            asm volatile("s_waitcnt vmcnt(8)" ::: "memory");  // current tile landed
        } else {
            asm volatile("s_waitcnt vmcnt(0)" ::: "memory");
        }
        __builtin_amdgcn_s_barrier();                     // raw: no vmcnt(0) drain
        __builtin_amdgcn_sched_barrier(0);

        const float* lq = cb;
        const float* lk = cb + 2048;
        const float* lE = cb + 4096;
        const float* lv = cb + 6144;
        #pragma unroll
        for (int tt = 0; tt < 16; ++tt) {
            float4 qA = *(const float4*)&lq[tt * 128 + part * 4];
            float4 qB = *(const float4*)&lq[tt * 128 + 64 + part * 4];
            float4 kA = *(const float4*)&lk[tt * 128 + part * 4];
            float4 kB = *(const float4*)&lk[tt * 128 + 64 + part * 4];
            float4 eA = *(const float4*)&lE[tt * 128 + part * 4];
            float4 eB = *(const float4*)&lE[tt * 128 + 64 + part * 4];
            float4 v0 = *(const float4*)&lv[tt * 128 + dvl];
            float4 v1 = *(const float4*)&lv[tt * 128 + dvl + 4];
            f32x2 q2[4] = {{qA.x,qA.y},{qA.z,qA.w},{qB.x,qB.y},{qB.z,qB.w}};
            f32x2 k2[4] = {{kA.x,kA.y},{kA.z,kA.w},{kB.x,kB.y},{kB.z,kB.w}};
            f32x2 e2[4] = {{eA.x,eA.y},{eA.z,eA.w},{eB.x,eB.y},{eB.z,eB.w}};
            f32x2 vp[4] = {{v0.x,v0.y},{v0.z,v0.w},{v1.x,v1.y},{v1.z,v1.w}};
            #pragma unroll
            for (int j = 0; j < 8; ++j) p[j] = (f32x2){0.f, 0.f};
            #pragma unroll
            for (int i = 0; i < 4; ++i) {
                pk_mul_ip(Lam[i], e2[i]);
                #pragma unroll
                for (int j = 0; j < 8; ++j) {
                    pk_mul_ip(S[i][j], e2[i]);            // S *= e
                    if (j & 1) pk_fma_bh(S[i][j], k2[i], vp[j >> 1]);  // S += k*v (bcast hi)
                    else       pk_fma_bl(S[i][j], k2[i], vp[j >> 1]);  // (bcast lo)
                    pk_fma_ip(p[j], q2[i], S[i][j]);      // p += q*S
                }
            }
            f32x2 pp0 = (f32x2){p[0].x + p[0].y, p[1].x + p[1].y};
            f32x2 pp1 = (f32x2){p[2].x + p[2].y, p[3].x + p[3].y};
            f32x2 pp2 = (f32x2){p[4].x + p[4].y, p[5].x + p[5].y};
            f32x2 pp3 = (f32x2){p[6].x + p[6].y, p[7].x + p[7].y};
            pp0 = dpp_red16_x2(pp0);
            pp1 = dpp_red16_x2(pp1);
            pp2 = dpp_red16_x2(pp2);
            pp3 = dpp_red16_x2(pp3);
            if (part == 0) {
                *(float4*)(o + oo)     = make_float4(pp0.x, pp0.y, pp1.x, pp1.y);
                *(float4*)(o + oo + 4) = make_float4(pp2.x, pp2.y, pp3.x, pp3.y);
            }
            oo += 1024;
            if (dvb == 0 && tid < 16) {  // q~ = q * Lam (one writer per dk)
                f32x2 a0 = q2[0] * Lam[0], a1 = q2[1] * Lam[1];
                f32x2 a2 = q2[2] * Lam[2], a3 = q2[3] * Lam[3];
                *(float4*)(qt + qo2)      = make_float4(a0.x, a0.y, a1.x, a1.y);
                *(float4*)(qt + qo2 + 64) = make_float4(a2.x, a2.y, a3.x, a3.y);
            }
            qo2 += 512;
        }
        __builtin_amdgcn_sched_barrier(0);
        __builtin_amdgcn_s_barrier();                     // all reads of cb done
    }

    // local end-state writeback
    float* sp = Sl + (((size_t)co * 16 + bh) << 15) + dv;
    #pragma unroll
    for (int i = 0; i < 4; ++i) {
        const int dke = (i < 2) ? part * 4 + i * 2 : 64 + part * 4 + (i - 2) * 2;
        *(float4*)&sp[(size_t)(dke + 0) * DVn] =
            make_float4(S[i][0].x, S[i][1].x, S[i][2].x, S[i][3].x);
        *(float4*)&sp[(size_t)(dke + 0) * DVn + 4] =
            make_float4(S[i][4].x, S[i][5].x, S[i][6].x, S[i][7].x);
        *(float4*)&sp[(size_t)(dke + 1) * DVn] =
            make_float4(S[i][0].y, S[i][1].y, S[i][2].y, S[i][3].y);
        *(float4*)&sp[(size_t)(dke + 1) * DVn + 4] =
            make_float4(S[i][4].y, S[i][5].y, S[i][6].y, S[i][7].y);
    }
    if (dvb == 0 && dvi == 0) {
        float* dp = Dc + (co * 16 + bh) * DKn;
        #pragma unroll
        for (int i = 0; i < 4; ++i) {
            const int dke = (i < 2) ? part * 4 + i * 2 : 64 + part * 4 + (i - 2) * 2;
            *(float2*)&dp[dke] = make_float2(Lam[i].x, Lam[i].y);
        }
    }
}

// sequential chunk combine (16 coarse chunks): overwrite Sl[c] with START state
__global__ __launch_bounds__(256) void combine(float* __restrict__ Sl,
                                               const float* __restrict__ Dc) {
    const int bh = blockIdx.y;
    const int e4 = blockIdx.x * 256 + threadIdx.x;
    const int dk = e4 >> 6;
    float4 s = make_float4(0.f, 0.f, 0.f, 0.f);
    #pragma unroll 4
    for (int c = 0; c < NCC; ++c) {
        float4* p = (float4*)(Sl + (((size_t)c * 16 + bh) << 15)) + e4;
        float4 local = *p;
        const float d = Dc[(c * 16 + bh) * DKn + dk];
        *p = s;
        s.x = s.x * d + local.x;  s.y = s.y * d + local.y;
        s.z = s.z * d + local.z;  s.w = s.w * d + local.w;
    }
}

// inter-chunk correction: o[t][dv] += sum_dk q~[t][dk] * S_start[dk][dv]
__global__ __launch_bounds__(256, 4) void fixup(const float* __restrict__ qt,
    const float* __restrict__ Sl, float* __restrict__ o)
{
    __shared__ __align__(16) float Aq[16][128];  // [kk][t]
    __shared__ __align__(16) float Bs[16][64];   // [kk][dv]
    const int raw = blockIdx.x;
    const int l = (raw & 7) * 128 + (raw >> 3);
    const int dvt = l & 3, bh = (l >> 2) & 15, co = l >> 6;
    const int b = bh >> 2, h = bh & 3;
    const int tid = threadIdx.x;
    const int tx = tid & 15, ty = tid >> 4;
    const int t0 = co * CLO;
    const int dv0 = dvt * 64;

    const float* qbase = qt + (size_t)(b * Tn + t0) * 512 + h * DKn;
    const float* sbase = Sl + (((size_t)co * 16 + bh) << 15) + dv0;

    float acc[8][4] = {};
    for (int k0 = 0; k0 < DKn; k0 += 16) {
        __syncthreads();
        #pragma unroll
        for (int s = 0; s < 2; ++s) {
            const int f = tid + s * 256;
            const int t = f >> 2, kk4 = (f & 3) << 2;
            float4 a = *(const float4*)&qbase[(size_t)t * 512 + k0 + kk4];
            Aq[kk4 + 0][t] = a.x; Aq[kk4 + 1][t] = a.y;
            Aq[kk4 + 2][t] = a.z; Aq[kk4 + 3][t] = a.w;
        }
        {
            const int dk = tid >> 4, dvq = (tid & 15) << 2;
            *(float4*)&Bs[dk][dvq] = *(const float4*)&sbase[(size_t)(k0 + dk) * DVn + dvq];
        }
        __syncthreads();
        #pragma unroll
        for (int kk = 0; kk < 16; ++kk) {
            float4 a0 = *(const float4*)&Aq[kk][ty * 8];
            float4 a1 = *(const float4*)&Aq[kk][ty * 8 + 4];
            float4 bv = *(const float4*)&Bs[kk][tx * 4];
            float ar[8] = {a0.x,a0.y,a0.z,a0.w,a1.x,a1.y,a1.z,a1.w};
            float br[4] = {bv.x,bv.y,bv.z,bv.w};
            #pragma unroll
            for (int i = 0; i < 8; ++i)
                #pragma unroll
                for (int j = 0; j < 4; ++j)
                    acc[i][j] += ar[i] * br[j];
        }
    }
    float* ob = o + (size_t)(b * Tn + t0) * 1024 + h * DVn + dv0;
    #pragma unroll
    for (int i = 0; i < 8; ++i) {
        float* row = ob + (size_t)(ty * 8 + i) * 1024 + tx * 4;
        float4 c = *(float4*)row;
        c.x += acc[i][0]; c.y += acc[i][1];
        c.z += acc[i][2]; c.w += acc[i][3];
        *(float4*)row = c;
    }
}

// ---------- RMSNorm + swish gate (g in bf16) -> bf16 ----------
__global__ __launch_bounds__(256) void rms_gate(const float* __restrict__ o,
    const ushort* __restrict__ gbf, const float* __restrict__ wt,
    ushort* __restrict__ obf)
{
    const int tid = threadIdx.x;
    const int w = tid >> 6, lane = tid & 63;
    const int row = blockIdx.x * 4 + w;
    const int n = row >> 2, h = row & 3;
    const size_t ob_base = (size_t)n * VDn + h * DVn + lane * 4;

    float4 o4 = *(const float4*)&o[ob_base];
    float ss = o4.x*o4.x + o4.y*o4.y + o4.z*o4.z + o4.w*o4.w;
    #pragma unroll
    for (int m = 1; m < 64; m <<= 1) ss += __shfl_xor(ss, m);
    const float r = rsqrtf(ss * (1.0f / DVn) + 1e-5f);

    ushort4 gu = *(const ushort4*)&gbf[ob_base];
    float gx = __uint_as_float((unsigned)gu.x << 16);
    float gy = __uint_as_float((unsigned)gu.y << 16);
    float gz = __uint_as_float((unsigned)gu.z << 16);
    float gw = __uint_as_float((unsigned)gu.w << 16);
    float4 w4 = *(const float4*)&wt[h * DVn + lane * 4];
    ushort4 u;
    u.x = f2bf(o4.x * r * w4.x * (gx / (1.0f + expf(-gx))));
    u.y = f2bf(o4.y * r * w4.y * (gy / (1.0f + expf(-gy))));
    u.z = f2bf(o4.z * r * w4.z * (gz / (1.0f + expf(-gz))));
    u.w = f2bf(o4.w * r * w4.w * (gw / (1.0f + expf(-gw))));
    *(ushort4*)&obf[ob_base] = u;
}

extern "C" void kernel_launch(void* const* d_in, const int* in_sizes, int n_in,
                              void* d_out, int out_size, void* d_ws, size_t ws_size,
                              hipStream_t stream) {
    const float* hs          = (const float*)d_in[0];
    const float* Wq          = (const float*)d_in[1];
    const float* Wk          = (const float*)d_in[2];
    const float* Wv          = (const float*)d_in[3];
    const float* Wg          = (const float*)d_in[4];
    const float* Wa          = (const float*)d_in[5];
    const float* Wo          = (const float*)d_in[6];
    const float* A_log_base  = (const float*)d_in[7];
    const float* A_log_delta = (const float*)d_in[8];
    const float* dt_bias     = (const float*)d_in[9];
    const float* gnw         = (const float*)d_in[10];
    float* out = (float*)d_out;

    char* ws = (char*)d_ws;
    float*  qk   = (float*)(ws);                           // 32MB [8192][1024] q|k
    float*  vb   = (float*)(ws + ((size_t)32  << 20));     // 32MB [8192][1024] v
    float*  Eb   = (float*)(ws + ((size_t)64  << 20));     // 16MB [8192][512]
    float*  Sl   = (float*)(ws + ((size_t)80  << 20));     // 32MB [16][16][128][256]
    float*  qtb  = (float*)(ws + ((size_t)112 << 20));     // 16MB [8192][512] q~
    float*  ob   = (float*)(ws + ((size_t)144 << 20));     // 32MB [8192][1024]
    ushort* hsb  = (ushort*)(ws + ((size_t)144 << 20));    // 16MB overlay on ob
    ushort* gbf  = (ushort*)(ws + ((size_t)176 << 20));    // 16MB [8192][1024] g bf16
    ushort* Wqkab= (ushort*)(ws + ((size_t)192 << 20));    //  3MB
    ushort* Wvgb = (ushort*)(ws + ((size_t)195 << 20));    //  4MB
    ushort* Wob  = (ushort*)(ws + ((size_t)199 << 20));    //  2MB
    float*  Dc   = (float*)(ws + ((size_t)201 << 20));     // 128KB [16][16][128]
    ushort* obf  = (ushort*)qk;                            // reuse qk after gla_scan

    // fused casts: hs + 6 weight matrices in one launch
    CastArgs ca;
    ca.src[0] = hs; ca.src[1] = Wq; ca.src[2] = Wk; ca.src[3] = Wa;
    ca.src[4] = Wv; ca.src[5] = Wg; ca.src[6] = Wo;
    ca.dst[0] = hsb;
    ca.dst[1] = Wqkab;
    ca.dst[2] = Wqkab + KDn * Dn;
    ca.dst[3] = Wqkab + 2 * KDn * Dn;
    ca.dst[4] = Wvgb;
    ca.dst[5] = Wvgb + VDn * Dn;
    ca.dst[6] = Wob;
    const int n4s[7] = {NROWS * Dn / 4, KDn * Dn / 4, KDn * Dn / 4, KDn * Dn / 4,
                        VDn * Dn / 4, VDn * Dn / 4, VDn * Dn / 4};
    ca.cum[0] = 0;
    for (int i = 0; i < 7; ++i) ca.cum[i + 1] = ca.cum[i] + n4s[i];
    cast_all<<<2048, 256, 0, stream>>>(ca);

    // projections
    mm2<1,12><<<768,  256, 0, stream>>>(hsb, Wqkab, qk, nullptr, Eb,
                                        dt_bias, A_log_base, A_log_delta);
    mm2<2,16><<<1024, 256, 0, stream>>>(hsb, Wvgb, vb, gbf, nullptr,
                                        nullptr, nullptr, nullptr);

    // single-pass scan + coarse combine + inter-chunk fixup
    gla_scan<<<512, 256, 0, stream>>>(qk, Eb, vb, ob, Sl, qtb, Dc);
    combine<<<dim3(32, 16), 256, 0, stream>>>(Sl, Dc);
    fixup<<<1024, 256, 0, stream>>>(qtb, Sl, ob);

    // epilogue
    rms_gate<<<NROWS * Hn / 4, 256, 0, stream>>>(ob, gbf, gnw, obf);
    mm2<0,8><<<512, 256, 0, stream>>>(obf, Wob, out, nullptr, nullptr,
                                      nullptr, nullptr, nullptr);
}

// Round 13
// 322.828 us; speedup vs baseline: 1.2107x; 1.1690x over previous
//
#include <hip/hip_runtime.h>
#include <math.h>

#define Bn   4
#define Tn   2048
#define Dn   1024
#define Hn   4
#define DKn  128
#define DVn  256
#define KDn  512
#define VDn  1024
#define NROWS 8192
#define NCC  32
#define CLEN 64
#define LOG_T_REF_F 6.2383246250395075f

using bf16x8 = __attribute__((ext_vector_type(8))) short;
using f32x4  = __attribute__((ext_vector_type(4))) float;

__device__ __forceinline__ float softplus_f(float x) {
    return fmaxf(x, 0.0f) + log1pf(expf(-fabsf(x)));
}
__device__ __forceinline__ ushort f2bf(float f) {
    unsigned u = __float_as_uint(f);
    u = (u + 0x7fffu + ((u >> 16) & 1u)) >> 16;
    return (ushort)u;
}
__device__ __forceinline__ float bf2f(ushort u) {
    return __uint_as_float((unsigned)u << 16);
}
__device__ __forceinline__ void gload16(const void* g, void* l) {
    __builtin_amdgcn_global_load_lds(
        (const __attribute__((address_space(1))) unsigned*)g,
        (__attribute__((address_space(3))) unsigned*)l, 16, 0, 0);
}

// ---------- fused fp32 -> bf16 cast over 7 segments ----------
struct CastArgs {
    const float* src[7];
    ushort* dst[7];
    int cum[8];
};
__global__ __launch_bounds__(256) void cast_all(CastArgs a) {
    const int total = a.cum[7];
    for (int i = blockIdx.x * 256 + threadIdx.x; i < total; i += gridDim.x * 256) {
        int s = 0;
        #pragma unroll
        for (int k = 1; k < 7; ++k) s += (i >= a.cum[k]) ? 1 : 0;
        const int off = i - a.cum[s];
        float4 v = *(const float4*)&a.src[s][(size_t)off * 4];
        ushort4 u;
        u.x = f2bf(v.x); u.y = f2bf(v.y); u.z = f2bf(v.z); u.w = f2bf(v.w);
        *(ushort4*)&a.dst[s][(size_t)off * 4] = u;
    }
}

// ---------- bf16 MFMA GEMM ----------
// MODE 1 epilogue (cols>=1024) now writes LOG decay gk (not exp(gk)).
template<int MODE, int NX>
__global__ __launch_bounds__(256) void mm2(const ushort* __restrict__ A,
    const ushort* __restrict__ Bw, float* __restrict__ C,
    ushort* __restrict__ C2, float* __restrict__ Eo,
    const float* __restrict__ dt_bias, const float* __restrict__ A_log_base,
    const float* __restrict__ A_log_delta)
{
    __shared__ __align__(16) ushort As[4][128][8];
    __shared__ __align__(16) ushort Bs[4][128][8];
    const int raw = blockIdx.x;
    const int nwg = NX * 64;
    const int l = (raw & 7) * (nwg >> 3) + (raw >> 3);
    const int bx = l % NX, by = l / NX;
    const int tid = threadIdx.x;
    const int lane = tid & 63, w = tid >> 6;
    const int l15 = lane & 15, lg = lane >> 4;
    const int wr = (w >> 1) << 6, wc = (w & 1) << 6;
    const int row0 = by << 7, col0 = bx << 7;

    const ushort* Ag0 = A  + (size_t)(row0 + lane) * Dn + w * 8;
    const ushort* Ag1 = A  + (size_t)(row0 + 64 + lane) * Dn + w * 8;
    const ushort* Bg0 = Bw + (size_t)(col0 + lane) * Dn + w * 8;
    const ushort* Bg1 = Bw + (size_t)(col0 + 64 + lane) * Dn + w * 8;
    ushort* lA0 = &As[w][0][0];
    ushort* lA1 = &As[w][64][0];
    ushort* lB0 = &Bs[w][0][0];
    ushort* lB1 = &Bs[w][64][0];

    f32x4 acc[4][4];
    #pragma unroll
    for (int m = 0; m < 4; ++m)
        #pragma unroll
        for (int n = 0; n < 4; ++n)
            acc[m][n] = (f32x4){0.f, 0.f, 0.f, 0.f};

    for (int kt = 0; kt < Dn; kt += 32) {
        __syncthreads();
        gload16(Ag0 + kt, lA0);
        gload16(Ag1 + kt, lA1);
        gload16(Bg0 + kt, lB0);
        gload16(Bg1 + kt, lB1);
        __syncthreads();
        bf16x8 af[4], bv[4];
        #pragma unroll
        for (int m = 0; m < 4; ++m) af[m] = *(const bf16x8*)&As[lg][wr + m*16 + l15][0];
        #pragma unroll
        for (int n = 0; n < 4; ++n) bv[n] = *(const bf16x8*)&Bs[lg][wc + n*16 + l15][0];
        #pragma unroll
        for (int m = 0; m < 4; ++m)
            #pragma unroll
            for (int n = 0; n < 4; ++n)
                acc[m][n] = __builtin_amdgcn_mfma_f32_16x16x32_bf16(af[m], bv[n], acc[m][n], 0, 0, 0);
    }

    if (MODE == 1 && col0 >= 1024) {
        const float base_ = A_log_base[0];
        const float s0 = softplus_f(A_log_delta[0]);
        const float s1 = softplus_f(A_log_delta[1]);
        const float s2 = softplus_f(A_log_delta[2]);
        const float c3 = s0 + s1 + s2;
        const float mg = c3 * (1.0f / 3.0f);
        float pf[4][4];
        #pragma unroll
        for (int m = 0; m < 4; ++m) {
            const int row = row0 + wr + m * 16 + lg * 4;
            #pragma unroll
            for (int r = 0; r < 4; ++r) {
                const int t = (row + r) & (Tn - 1);
                pf[m][r] = logf((float)(t + 1));
            }
        }
        #pragma unroll
        for (int n = 0; n < 4; ++n) {
            const int dk = col0 - 1024 + wc + n * 16 + l15;
            const int h = dk >> 7;
            const float cumh = (h == 0) ? 0.f : (h == 1) ? s0 : (h == 2) ? s0 + s1 : c3;
            float alpha = (float)(3 - h) * (1.0f / 3.0f)
                        + (cumh - (float)h * mg) * (1.0f / LOG_T_REF_F);
            alpha = fminf(fmaxf(alpha, 0.0f), 1.0f);
            const float expA = expf(base_ + cumh);
            const float db = dt_bias[dk];
            #pragma unroll
            for (int m = 0; m < 4; ++m) {
                const int row = row0 + wr + m * 16 + lg * 4;
                #pragma unroll
                for (int r = 0; r < 4; ++r) {
                    const float p = expf(-alpha * pf[m][r]);
                    // LOG decay gk (<= 0), not exp(gk)
                    Eo[(size_t)(row + r) * KDn + dk] =
                        -expA * softplus_f(acc[m][n][r] + db) * p;
                }
            }
        }
    } else if (MODE == 2 && col0 >= 1024) {
        #pragma unroll
        for (int m = 0; m < 4; ++m) {
            const int row = row0 + wr + m * 16 + lg * 4;
            #pragma unroll
            for (int n = 0; n < 4; ++n) {
                const int col = col0 - 1024 + wc + n * 16 + l15;
                #pragma unroll
                for (int r = 0; r < 4; ++r)
                    C2[(size_t)(row + r) * 1024 + col] = f2bf(acc[m][n][r]);
            }
        }
    } else {
        const float s = (MODE == 1 && col0 < 512) ? 0.08838834764831845f : 1.0f;
        #pragma unroll
        for (int m = 0; m < 4; ++m) {
            const int row = row0 + wr + m * 16 + lg * 4;
            #pragma unroll
            for (int n = 0; n < 4; ++n) {
                const int col = col0 + wc + n * 16 + l15;
                #pragma unroll
                for (int r = 0; r < 4; ++r)
                    C[(size_t)(row + r) * 1024 + col] = acc[m][n][r] * s;
            }
        }
    }
}

// ---------- chunked GLA, log-space attention form (all exp args <= 0) ----------
// One 1024-thread block per (co, bh). chunk 64, sub-chunks of 16.
// LDS (bytes): g f32[64][132]@0; qraw bf16[64][136]@33792; kraw@51200; Qb@68608;
//   Koff bf16[96][136]@86016 (K1 rows0-15 ref g15 | K2 rows16-47 ref g31 |
//   K3 rows48-95 ref g47); KhT bf16[128][72]@112128; At bf16[64][72]@130560.
//   VT bf16[256][72] overlays @0 after QK phase. qsum f32[4][128] temp @86016.
// Total 139776.
__global__ __launch_bounds__(1024) void gla_chunk(
    float* qk, const float* __restrict__ Gb, const float* __restrict__ vb,
    float* __restrict__ o, float* __restrict__ Sl, float* __restrict__ Dc)
{
    extern __shared__ __align__(16) char smem[];
    float*  g    = (float*)smem;
    ushort* qraw = (ushort*)(smem + 33792);
    ushort* kraw = (ushort*)(smem + 51200);
    ushort* Qb   = (ushort*)(smem + 68608);
    ushort* Koff = (ushort*)(smem + 86016);
    ushort* KhT  = (ushort*)(smem + 112128);
    ushort* At   = (ushort*)(smem + 130560);
    ushort* VT   = (ushort*)smem;            // overlay (phase >= 4)
    float*  qsum = (float*)(smem + 86016);   // phase-1 temp inside Koff region

    const int bid = blockIdx.x;
    const int co = bid >> 4, bh = bid & 15;
    const int b = bh >> 2, h = bh & 3;
    const int tid = threadIdx.x;
    const int w = tid >> 6, lane = tid & 63;
    const int l15 = lane & 15, lg = lane >> 4;
    const size_t rowbase = (size_t)(b * Tn + co * CLEN);

    // ---- phase 1: inclusive cumsum of gk -> g[64][132] ----
    float c16[16];
    int dk1 = 0, qr1 = 0;
    if (tid < 512) {
        dk1 = tid & 127; qr1 = tid >> 7;
        const float* gp = Gb + (rowbase + qr1 * 16) * 512 + h * 128 + dk1;
        float run = 0.f;
        #pragma unroll
        for (int s = 0; s < 16; ++s) { run += gp[(size_t)s * 512]; c16[s] = run; }
        qsum[qr1 * 128 + dk1] = run;
    }
    __syncthreads();
    if (tid < 512) {
        float pre = 0.f;
        for (int r = 0; r < qr1; ++r) pre += qsum[r * 128 + dk1];
        #pragma unroll
        for (int s = 0; s < 16; ++s) g[(qr1 * 16 + s) * 132 + dk1] = c16[s] + pre;
    }
    __syncthreads();

    // ---- phase 2: operand builds (all exp args <= 0) ----
    #pragma unroll
    for (int it = 0; it < 8; ++it) {
        const int idx = tid + it * 1024;
        const int t = idx >> 7, dk = idx & 127;
        const float gi = g[t * 132 + dk];
        const size_t qaddr = (rowbase + t) * 1024 + h * 128 + dk;
        const float qv = qk[qaddr];
        const float gr = (t < 16) ? 0.f : g[(16 * (t >> 4) - 1) * 132 + dk];
        Qb[t * 136 + dk] = f2bf(qv * __expf(gi - gr));
        qraw[t * 136 + dk] = f2bf(qv);
        qk[qaddr] = qv * __expf(gi);           // q~ in place (for fixup)
        const float kv = qk[qaddr + 512];
        kraw[t * 136 + dk] = f2bf(kv);
        KhT[dk * 72 + t] = f2bf(kv * __expf(g[63 * 132 + dk] - gi));
        if (t < 16) Koff[t * 136 + dk]        = f2bf(kv * __expf(g[15 * 132 + dk] - gi));
        if (t < 32) Koff[(16 + t) * 136 + dk] = f2bf(kv * __expf(g[31 * 132 + dk] - gi));
        if (t < 48) Koff[(48 + t) * 136 + dk] = f2bf(kv * __expf(g[47 * 132 + dk] - gi));
    }
    for (int i = tid; i < 2304; i += 1024) ((int*)At)[i] = 0;   // zero At
    if (tid < 128)
        Dc[(co * 16 + bh) * 128 + tid] = __expf(g[63 * 132 + tid]);
    __syncthreads();

    // ---- phase 3: QK -> At ----
    if (w < 6) {            // off-diagonal sub-chunk tiles (MFMA)
        const int Tt[6] = {16, 32, 32, 48, 48, 48};
        const int Ss[6] = { 0,  0, 16,  0, 16, 32};
        const int Kb[6] = { 0, 16, 16, 48, 48, 48};
        const int T = Tt[w], S = Ss[w], KB = Kb[w];
        f32x4 acc = (f32x4){0.f, 0.f, 0.f, 0.f};
        #pragma unroll
        for (int kk = 0; kk < 4; ++kk) {
            bf16x8 a  = *(const bf16x8*)&Qb[(T + l15) * 136 + kk * 32 + lg * 8];
            bf16x8 bb = *(const bf16x8*)&Koff[(KB + S + l15) * 136 + kk * 32 + lg * 8];
            acc = __builtin_amdgcn_mfma_f32_16x16x32_bf16(a, bb, acc, 0, 0, 0);
        }
        #pragma unroll
        for (int r = 0; r < 4; ++r)
            At[(T + lg * 4 + r) * 72 + S + l15] = f2bf(acc[r]);
    } else if (w < 14) {    // diagonal 16x16 blocks (scalar, masked, log-space)
        const int d = (w - 6) >> 1, hf = (w - 6) & 1;
        #pragma unroll
        for (int pp = 0; pp < 2; ++pp) {
            const int p = hf * 128 + pp * 64 + lane;
            const int i_ = p >> 4, j_ = p & 15;
            if (j_ <= i_) {
                const int ti = d * 16 + i_, tj = d * 16 + j_;
                float a = 0.f;
                for (int dk = 0; dk < 128; ++dk) {
                    const float qf = bf2f(qraw[ti * 136 + dk]);
                    const float kf = bf2f(kraw[tj * 136 + dk]);
                    a += qf * kf * __expf(g[ti * 132 + dk] - g[tj * 132 + dk]);
                }
                At[ti * 72 + tj] = f2bf(a);
            }
        }
    }
    __syncthreads();

    // ---- phase 4: V^T build (overlays dead g/qraw region) ----
    {
        const int dv4 = (tid & 63) * 4, tseg = tid >> 6;
        float4 vv[4];
        #pragma unroll
        for (int s = 0; s < 4; ++s)
            vv[s] = *(const float4*)&vb[(rowbase + tseg * 4 + s) * 1024 + h * 256 + dv4];
        const float* vf = (const float*)vv;
        #pragma unroll
        for (int c = 0; c < 4; ++c) {
            int lo = (unsigned)f2bf(vf[0 * 4 + c]) | ((unsigned)f2bf(vf[1 * 4 + c]) << 16);
            int hi = (unsigned)f2bf(vf[2 * 4 + c]) | ((unsigned)f2bf(vf[3 * 4 + c]) << 16);
            *(int2*)((char*)VT + (size_t)(dv4 + c) * 144 + tseg * 8) = make_int2(lo, hi);
        }
    }
    __syncthreads();

    // ---- phase 5: PV (o intra) + state S_local (MFMA) ----
    float* sp = Sl + (((size_t)co * 16 + bh) << 15);
    for (int id = w; id < 192; id += 16) {
        if (id < 64) {
            const int mt = id >> 4, nt = id & 15;
            f32x4 acc = (f32x4){0.f, 0.f, 0.f, 0.f};
            #pragma unroll
            for (int kk = 0; kk < 2; ++kk) {
                bf16x8 a  = *(const bf16x8*)&At[(mt * 16 + l15) * 72 + kk * 32 + lg * 8];
                bf16x8 bb = *(const bf16x8*)&VT[(nt * 16 + l15) * 72 + kk * 32 + lg * 8];
                acc = __builtin_amdgcn_mfma_f32_16x16x32_bf16(a, bb, acc, 0, 0, 0);
            }
            #pragma unroll
            for (int r = 0; r < 4; ++r)
                o[(rowbase + mt * 16 + lg * 4 + r) * 1024 + h * 256 + nt * 16 + l15] = acc[r];
        } else {
            const int sid = id - 64;
            const int mt = sid >> 4, nt = sid & 15;
            f32x4 acc = (f32x4){0.f, 0.f, 0.f, 0.f};
            #pragma unroll
            for (int kk = 0; kk < 2; ++kk) {
                bf16x8 a  = *(const bf16x8*)&KhT[(mt * 16 + l15) * 72 + kk * 32 + lg * 8];
                bf16x8 bb = *(const bf16x8*)&VT[(nt * 16 + l15) * 72 + kk * 32 + lg * 8];
                acc = __builtin_amdgcn_mfma_f32_16x16x32_bf16(a, bb, acc, 0, 0, 0);
            }
            #pragma unroll
            for (int r = 0; r < 4; ++r)
                sp[(size_t)(mt * 16 + lg * 4 + r) * 256 + nt * 16 + l15] = acc[r];
        }
    }
}

// sequential chunk combine (32 chunks): overwrite Sl[c] with chunk-c START state
__global__ __launch_bounds__(256) void combine(float* __restrict__ Sl,
                                               const float* __restrict__ Dc) {
    const int bh = blockIdx.y;
    const int e4 = blockIdx.x * 256 + threadIdx.x;
    const int dk = e4 >> 6;
    float4 s = make_float4(0.f, 0.f, 0.f, 0.f);
    #pragma unroll 4
    for (int c = 0; c < NCC; ++c) {
        float4* p = (float4*)(Sl + (((size_t)c * 16 + bh) << 15)) + e4;
        float4 local = *p;
        const float d = Dc[(c * 16 + bh) * DKn + dk];
        *p = s;
        s.x = s.x * d + local.x;  s.y = s.y * d + local.y;
        s.z = s.z * d + local.z;  s.w = s.w * d + local.w;
    }
}

// inter-chunk correction: o[t][dv] += sum_dk q~[t][dk] * S_start[dk][dv]
__global__ __launch_bounds__(256, 4) void fixup(const float* __restrict__ qt,
    const float* __restrict__ Sl, float* __restrict__ o)
{
    __shared__ __align__(16) float Aq[16][68];
    __shared__ __align__(16) float Bs[16][68];
    const int raw = blockIdx.x;
    const int l = (raw & 7) * 256 + (raw >> 3);
    const int dvt = l & 3, bh = (l >> 2) & 15, co = l >> 6;
    const int b = bh >> 2, h = bh & 3;
    const int tid = threadIdx.x;
    const int tx = tid & 15, ty = tid >> 4;
    const int t0 = co * CLEN;
    const int dv0 = dvt * 64;

    const float* qbase = qt + (size_t)(b * Tn + t0) * 1024 + h * 128;
    const float* sbase = Sl + (((size_t)co * 16 + bh) << 15) + dv0;

    float acc[4][4] = {};
    for (int k0 = 0; k0 < DKn; k0 += 16) {
        __syncthreads();
        {
            const int t = tid >> 2, kk4 = (tid & 3) << 2;
            float4 a = *(const float4*)&qbase[(size_t)t * 1024 + k0 + kk4];
            Aq[kk4 + 0][t] = a.x; Aq[kk4 + 1][t] = a.y;
            Aq[kk4 + 2][t] = a.z; Aq[kk4 + 3][t] = a.w;
        }
        {
            const int dk = tid >> 4, dvq = (tid & 15) << 2;
            *(float4*)&Bs[dk][dvq] = *(const float4*)&sbase[(size_t)(k0 + dk) * 256 + dvq];
        }
        __syncthreads();
        #pragma unroll
        for (int kk = 0; kk < 16; ++kk) {
            float4 a  = *(const float4*)&Aq[kk][ty * 4];
            float4 bv = *(const float4*)&Bs[kk][tx * 4];
            float ar[4] = {a.x, a.y, a.z, a.w};
            float br[4] = {bv.x, bv.y, bv.z, bv.w};
            #pragma unroll
            for (int i = 0; i < 4; ++i)
                #pragma unroll
                for (int j = 0; j < 4; ++j)
                    acc[i][j] += ar[i] * br[j];
        }
    }
    float* obp = o + (size_t)(b * Tn + t0) * 1024 + h * 256 + dv0;
    #pragma unroll
    for (int i = 0; i < 4; ++i) {
        float* row = obp + (size_t)(ty * 4 + i) * 1024 + tx * 4;
        float4 c = *(float4*)row;
        c.x += acc[i][0]; c.y += acc[i][1];
        c.z += acc[i][2]; c.w += acc[i][3];
        *(float4*)row = c;
    }
}

// ---------- RMSNorm + swish gate (g in bf16) -> bf16 ----------
__global__ __launch_bounds__(256) void rms_gate(const float* __restrict__ o,
    const ushort* __restrict__ gbf, const float* __restrict__ wt,
    ushort* __restrict__ obf)
{
    const int tid = threadIdx.x;
    const int w = tid >> 6, lane = tid & 63;
    const int row = blockIdx.x * 4 + w;
    const int n = row >> 2, h = row & 3;
    const size_t ob_base = (size_t)n * VDn + h * DVn + lane * 4;

    float4 o4 = *(const float4*)&o[ob_base];
    float ss = o4.x*o4.x + o4.y*o4.y + o4.z*o4.z + o4.w*o4.w;
    #pragma unroll
    for (int m = 1; m < 64; m <<= 1) ss += __shfl_xor(ss, m);
    const float r = rsqrtf(ss * (1.0f / DVn) + 1e-5f);

    ushort4 gu = *(const ushort4*)&gbf[ob_base];
    float gx = bf2f(gu.x), gy = bf2f(gu.y), gz = bf2f(gu.z), gw = bf2f(gu.w);
    float4 w4 = *(const float4*)&wt[h * DVn + lane * 4];
    ushort4 u;
    u.x = f2bf(o4.x * r * w4.x * (gx / (1.0f + expf(-gx))));
    u.y = f2bf(o4.y * r * w4.y * (gy / (1.0f + expf(-gy))));
    u.z = f2bf(o4.z * r * w4.z * (gz / (1.0f + expf(-gz))));
    u.w = f2bf(o4.w * r * w4.w * (gw / (1.0f + expf(-gw))));
    *(ushort4*)&obf[ob_base] = u;
}

extern "C" void kernel_launch(void* const* d_in, const int* in_sizes, int n_in,
                              void* d_out, int out_size, void* d_ws, size_t ws_size,
                              hipStream_t stream) {
    const float* hs          = (const float*)d_in[0];
    const float* Wq          = (const float*)d_in[1];
    const float* Wk          = (const float*)d_in[2];
    const float* Wv          = (const float*)d_in[3];
    const float* Wg          = (const float*)d_in[4];
    const float* Wa          = (const float*)d_in[5];
    const float* Wo          = (const float*)d_in[6];
    const float* A_log_base  = (const float*)d_in[7];
    const float* A_log_delta = (const float*)d_in[8];
    const float* dt_bias     = (const float*)d_in[9];
    const float* gnw         = (const float*)d_in[10];
    float* out = (float*)d_out;

    char* ws = (char*)d_ws;
    float*  qk   = (float*)(ws);                           // 32MB [8192][1024] q|k (q~ in place)
    float*  vb   = (float*)(ws + ((size_t)32  << 20));     // 32MB [8192][1024] v
    float*  Gbuf = (float*)(ws + ((size_t)64  << 20));     // 16MB [8192][512] log-decay
    float*  Sl   = (float*)(ws + ((size_t)80  << 20));     // 64MB [32][16][128][256]
    float*  ob   = (float*)(ws + ((size_t)144 << 20));     // 32MB [8192][1024]
    ushort* hsb  = (ushort*)(ws + ((size_t)144 << 20));    // 16MB overlay on ob
    ushort* gbf  = (ushort*)(ws + ((size_t)176 << 20));    // 16MB [8192][1024] g bf16
    ushort* Wqkab= (ushort*)(ws + ((size_t)192 << 20));    //  3MB
    ushort* Wvgb = (ushort*)(ws + ((size_t)195 << 20));    //  4MB
    ushort* Wob  = (ushort*)(ws + ((size_t)199 << 20));    //  2MB
    float*  Dc   = (float*)(ws + ((size_t)201 << 20));     // 256KB [32*16][128]
    ushort* obf  = (ushort*)qk;                            // reuse qk after fixup

    // fused casts
    CastArgs ca;
    ca.src[0] = hs; ca.src[1] = Wq; ca.src[2] = Wk; ca.src[3] = Wa;
    ca.src[4] = Wv; ca.src[5] = Wg; ca.src[6] = Wo;
    ca.dst[0] = hsb;
    ca.dst[1] = Wqkab;
    ca.dst[2] = Wqkab + KDn * Dn;
    ca.dst[3] = Wqkab + 2 * KDn * Dn;
    ca.dst[4] = Wvgb;
    ca.dst[5] = Wvgb + VDn * Dn;
    ca.dst[6] = Wob;
    const int n4s[7] = {NROWS * Dn / 4, KDn * Dn / 4, KDn * Dn / 4, KDn * Dn / 4,
                        VDn * Dn / 4, VDn * Dn / 4, VDn * Dn / 4};
    ca.cum[0] = 0;
    for (int i = 0; i < 7; ++i) ca.cum[i + 1] = ca.cum[i] + n4s[i];
    cast_all<<<2048, 256, 0, stream>>>(ca);

    // projections (MODE1 writes gk log-decay into Gbuf)
    mm2<1,12><<<768,  256, 0, stream>>>(hsb, Wqkab, qk, nullptr, Gbuf,
                                        dt_bias, A_log_base, A_log_delta);
    mm2<2,16><<<1024, 256, 0, stream>>>(hsb, Wvgb, vb, gbf, nullptr,
                                        nullptr, nullptr, nullptr);

    // chunked recurrence: log-space attention form
    (void)hipFuncSetAttribute((const void*)gla_chunk,
                              hipFuncAttributeMaxDynamicSharedMemorySize, 139776);
    gla_chunk<<<512, 1024, 139776, stream>>>(qk, Gbuf, vb, ob, Sl, Dc);
    combine<<<dim3(32, 16), 256, 0, stream>>>(Sl, Dc);
    fixup<<<2048, 256, 0, stream>>>(qk, Sl, ob);

    // epilogue
    rms_gate<<<NROWS * Hn / 4, 256, 0, stream>>>(ob, gbf, gnw, obf);
    mm2<0,8><<<512, 256, 0, stream>>>(obf, Wob, out, nullptr, nullptr,
                                      nullptr, nullptr, nullptr);
}

// Round 14
// 309.071 us; speedup vs baseline: 1.2646x; 1.0445x over previous
//
#include <hip/hip_runtime.h>
#include <math.h>

#define Bn   4
#define Tn   2048
#define Dn   1024
#define Hn   4
#define DKn  128
#define DVn  256
#define KDn  512
#define VDn  1024
#define NROWS 8192
#define NCC  32
#define CLEN 64
#define LOG_T_REF_F 6.2383246250395075f

using bf16x8 = __attribute__((ext_vector_type(8))) short;
using f32x4  = __attribute__((ext_vector_type(4))) float;

__device__ __forceinline__ float softplus_f(float x) {
    return fmaxf(x, 0.0f) + log1pf(expf(-fabsf(x)));
}
__device__ __forceinline__ ushort f2bf(float f) {
    unsigned u = __float_as_uint(f);
    u = (u + 0x7fffu + ((u >> 16) & 1u)) >> 16;
    return (ushort)u;
}
__device__ __forceinline__ float bf2f(ushort u) {
    return __uint_as_float((unsigned)u << 16);
}
__device__ __forceinline__ void gload16(const void* g, void* l) {
    __builtin_amdgcn_global_load_lds(
        (const __attribute__((address_space(1))) unsigned*)g,
        (__attribute__((address_space(3))) unsigned*)l, 16, 0, 0);
}

// ---------- fused fp32 -> bf16 cast over 7 segments ----------
struct CastArgs {
    const float* src[7];
    ushort* dst[7];
    int cum[8];
};
__global__ __launch_bounds__(256) void cast_all(CastArgs a) {
    const int total = a.cum[7];
    for (int i = blockIdx.x * 256 + threadIdx.x; i < total; i += gridDim.x * 256) {
        int s = 0;
        #pragma unroll
        for (int k = 1; k < 7; ++k) s += (i >= a.cum[k]) ? 1 : 0;
        const int off = i - a.cum[s];
        float4 v = *(const float4*)&a.src[s][(size_t)off * 4];
        ushort4 u;
        u.x = f2bf(v.x); u.y = f2bf(v.y); u.z = f2bf(v.z); u.w = f2bf(v.w);
        *(ushort4*)&a.dst[s][(size_t)off * 4] = u;
    }
}

// ---------- bf16 MFMA GEMM, BK=64, XCD-swizzled ----------
// A[8192 x 1024] @ Bw[NX*128 x 1024]^T, fp32 accumulate. Grid = NX*64 blocks.
// MODE 0: plain fp32 -> C [.][1024]
// MODE 1 (fused projection, NX=28, weights q|k|a|v|g concatenated):
//   col0 <  1024 : qk fp32 (cols<512 scaled by DK^-0.5)
//   col0 <  1536 : gate transform -> Eo [.][512] (LOG decay gk <= 0)
//   else         : cv=col0-1536; cv<1024 -> Cv (v fp32 [.][1024]);
//                  else -> C2 (g bf16 [.][1024])
template<int MODE, int NX>
__global__ __launch_bounds__(256) void mm3(const ushort* __restrict__ A,
    const ushort* __restrict__ Bw, float* __restrict__ C,
    float* __restrict__ Cv, ushort* __restrict__ C2, float* __restrict__ Eo,
    const float* __restrict__ dt_bias, const float* __restrict__ A_log_base,
    const float* __restrict__ A_log_delta)
{
    __shared__ __align__(16) ushort As[8][128][8];   // 16KB: k-slot s = k in [s*8, s*8+8)
    __shared__ __align__(16) ushort Bs[8][128][8];
    const int raw = blockIdx.x;
    const int nwg = NX * 64;
    const int l = (raw & 7) * (nwg >> 3) + (raw >> 3);   // XCD-chunked remap
    const int bx = l % NX, by = l / NX;
    const int tid = threadIdx.x;
    const int lane = tid & 63, w = tid >> 6;
    const int l15 = lane & 15, lg = lane >> 4;
    const int wr = (w >> 1) << 6, wc = (w & 1) << 6;
    const int row0 = by << 7, col0 = bx << 7;

    const ushort* A0 = A  + (size_t)(row0 + lane) * Dn + w * 8;
    const ushort* A1 = A  + (size_t)(row0 + 64 + lane) * Dn + w * 8;
    const ushort* B0 = Bw + (size_t)(col0 + lane) * Dn + w * 8;
    const ushort* B1 = Bw + (size_t)(col0 + 64 + lane) * Dn + w * 8;

    f32x4 acc[4][4];
    #pragma unroll
    for (int m = 0; m < 4; ++m)
        #pragma unroll
        for (int n = 0; n < 4; ++n)
            acc[m][n] = (f32x4){0.f, 0.f, 0.f, 0.f};

    for (int kt = 0; kt < Dn; kt += 64) {
        __syncthreads();
        // wave w stages slots w and w+4 (k offsets w*8 and w*8+32), both row halves
        gload16(A0 + kt,      &As[w][0][0]);
        gload16(A0 + kt + 32, &As[w + 4][0][0]);
        gload16(A1 + kt,      &As[w][64][0]);
        gload16(A1 + kt + 32, &As[w + 4][64][0]);
        gload16(B0 + kt,      &Bs[w][0][0]);
        gload16(B0 + kt + 32, &Bs[w + 4][0][0]);
        gload16(B1 + kt,      &Bs[w][64][0]);
        gload16(B1 + kt + 32, &Bs[w + 4][64][0]);
        __syncthreads();
        #pragma unroll
        for (int ks = 0; ks < 2; ++ks) {
            bf16x8 af[4], bv[4];
            #pragma unroll
            for (int m = 0; m < 4; ++m)
                af[m] = *(const bf16x8*)&As[ks * 4 + lg][wr + m * 16 + l15][0];
            #pragma unroll
            for (int n = 0; n < 4; ++n)
                bv[n] = *(const bf16x8*)&Bs[ks * 4 + lg][wc + n * 16 + l15][0];
            #pragma unroll
            for (int m = 0; m < 4; ++m)
                #pragma unroll
                for (int n = 0; n < 4; ++n)
                    acc[m][n] = __builtin_amdgcn_mfma_f32_16x16x32_bf16(af[m], bv[n], acc[m][n], 0, 0, 0);
        }
    }

    if (MODE == 1 && col0 >= 1024 && col0 < 1536) {
        // gate-transform epilogue -> LOG decay gk (<= 0)
        const float base_ = A_log_base[0];
        const float s0 = softplus_f(A_log_delta[0]);
        const float s1 = softplus_f(A_log_delta[1]);
        const float s2 = softplus_f(A_log_delta[2]);
        const float c3 = s0 + s1 + s2;
        const float mg = c3 * (1.0f / 3.0f);
        float pf[4][4];
        #pragma unroll
        for (int m = 0; m < 4; ++m) {
            const int row = row0 + wr + m * 16 + lg * 4;
            #pragma unroll
            for (int r = 0; r < 4; ++r) {
                const int t = (row + r) & (Tn - 1);
                pf[m][r] = logf((float)(t + 1));
            }
        }
        #pragma unroll
        for (int n = 0; n < 4; ++n) {
            const int dk = col0 - 1024 + wc + n * 16 + l15;   // 0..511
            const int h = dk >> 7;
            const float cumh = (h == 0) ? 0.f : (h == 1) ? s0 : (h == 2) ? s0 + s1 : c3;
            float alpha = (float)(3 - h) * (1.0f / 3.0f)
                        + (cumh - (float)h * mg) * (1.0f / LOG_T_REF_F);
            alpha = fminf(fmaxf(alpha, 0.0f), 1.0f);
            const float expA = expf(base_ + cumh);
            const float db = dt_bias[dk];
            #pragma unroll
            for (int m = 0; m < 4; ++m) {
                const int row = row0 + wr + m * 16 + lg * 4;
                #pragma unroll
                for (int r = 0; r < 4; ++r) {
                    const float p = expf(-alpha * pf[m][r]);
                    Eo[(size_t)(row + r) * KDn + dk] =
                        -expA * softplus_f(acc[m][n][r] + db) * p;
                }
            }
        }
    } else if (MODE == 1 && col0 >= 1536) {
        const int cv0 = col0 - 1536;
        if (cv0 < 1024) {   // v fp32
            #pragma unroll
            for (int m = 0; m < 4; ++m) {
                const int row = row0 + wr + m * 16 + lg * 4;
                #pragma unroll
                for (int n = 0; n < 4; ++n) {
                    const int col = cv0 + wc + n * 16 + l15;
                    #pragma unroll
                    for (int r = 0; r < 4; ++r)
                        Cv[(size_t)(row + r) * 1024 + col] = acc[m][n][r];
                }
            }
        } else {            // g bf16
            #pragma unroll
            for (int m = 0; m < 4; ++m) {
                const int row = row0 + wr + m * 16 + lg * 4;
                #pragma unroll
                for (int n = 0; n < 4; ++n) {
                    const int col = cv0 - 1024 + wc + n * 16 + l15;
                    #pragma unroll
                    for (int r = 0; r < 4; ++r)
                        C2[(size_t)(row + r) * 1024 + col] = f2bf(acc[m][n][r]);
                }
            }
        }
    } else {
        const float s = (MODE == 1 && col0 < 512) ? 0.08838834764831845f : 1.0f;
        #pragma unroll
        for (int m = 0; m < 4; ++m) {
            const int row = row0 + wr + m * 16 + lg * 4;
            #pragma unroll
            for (int n = 0; n < 4; ++n) {
                const int col = col0 + wc + n * 16 + l15;
                #pragma unroll
                for (int r = 0; r < 4; ++r)
                    C[(size_t)(row + r) * 1024 + col] = acc[m][n][r] * s;
            }
        }
    }
}

// ---------- chunked GLA, log-space attention form (all exp args <= 0) ----------
// One 1024-thread block per (co, bh). chunk 64, sub-chunks of 16.
__global__ __launch_bounds__(1024) void gla_chunk(
    float* qk, const float* __restrict__ Gb, const float* __restrict__ vb,
    float* __restrict__ o, float* __restrict__ Sl, float* __restrict__ Dc)
{
    extern __shared__ __align__(16) char smem[];
    float*  g    = (float*)smem;
    ushort* qraw = (ushort*)(smem + 33792);
    ushort* kraw = (ushort*)(smem + 51200);
    ushort* Qb   = (ushort*)(smem + 68608);
    ushort* Koff = (ushort*)(smem + 86016);
    ushort* KhT  = (ushort*)(smem + 112128);
    ushort* At   = (ushort*)(smem + 130560);
    ushort* VT   = (ushort*)smem;            // overlay (phase >= 4)
    float*  qsum = (float*)(smem + 86016);   // phase-1 temp inside Koff region

    const int bid = blockIdx.x;
    const int co = bid >> 4, bh = bid & 15;
    const int b = bh >> 2, h = bh & 3;
    const int tid = threadIdx.x;
    const int w = tid >> 6, lane = tid & 63;
    const int l15 = lane & 15, lg = lane >> 4;
    const size_t rowbase = (size_t)(b * Tn + co * CLEN);

    // ---- phase 1: inclusive cumsum of gk -> g[64][132] ----
    float c16[16];
    int dk1 = 0, qr1 = 0;
    if (tid < 512) {
        dk1 = tid & 127; qr1 = tid >> 7;
        const float* gp = Gb + (rowbase + qr1 * 16) * 512 + h * 128 + dk1;
        float run = 0.f;
        #pragma unroll
        for (int s = 0; s < 16; ++s) { run += gp[(size_t)s * 512]; c16[s] = run; }
        qsum[qr1 * 128 + dk1] = run;
    }
    __syncthreads();
    if (tid < 512) {
        float pre = 0.f;
        for (int r = 0; r < qr1; ++r) pre += qsum[r * 128 + dk1];
        #pragma unroll
        for (int s = 0; s < 16; ++s) g[(qr1 * 16 + s) * 132 + dk1] = c16[s] + pre;
    }
    __syncthreads();

    // ---- phase 2: operand builds (all exp args <= 0) ----
    #pragma unroll
    for (int it = 0; it < 8; ++it) {
        const int idx = tid + it * 1024;
        const int t = idx >> 7, dk = idx & 127;
        const float gi = g[t * 132 + dk];
        const size_t qaddr = (rowbase + t) * 1024 + h * 128 + dk;
        const float qv = qk[qaddr];
        const float gr = (t < 16) ? 0.f : g[(16 * (t >> 4) - 1) * 132 + dk];
        Qb[t * 136 + dk] = f2bf(qv * __expf(gi - gr));
        qraw[t * 136 + dk] = f2bf(qv);
        qk[qaddr] = qv * __expf(gi);           // q~ in place (for fixup)
        const float kv = qk[qaddr + 512];
        kraw[t * 136 + dk] = f2bf(kv);
        KhT[dk * 72 + t] = f2bf(kv * __expf(g[63 * 132 + dk] - gi));
        if (t < 16) Koff[t * 136 + dk]        = f2bf(kv * __expf(g[15 * 132 + dk] - gi));
        if (t < 32) Koff[(16 + t) * 136 + dk] = f2bf(kv * __expf(g[31 * 132 + dk] - gi));
        if (t < 48) Koff[(48 + t) * 136 + dk] = f2bf(kv * __expf(g[47 * 132 + dk] - gi));
    }
    for (int i = tid; i < 2304; i += 1024) ((int*)At)[i] = 0;   // zero At
    if (tid < 128)
        Dc[(co * 16 + bh) * 128 + tid] = __expf(g[63 * 132 + tid]);
    __syncthreads();

    // ---- phase 3: QK -> At ----
    if (w < 6) {            // off-diagonal sub-chunk tiles (MFMA)
        const int Tt[6] = {16, 32, 32, 48, 48, 48};
        const int Ss[6] = { 0,  0, 16,  0, 16, 32};
        const int Kb[6] = { 0, 16, 16, 48, 48, 48};
        const int T = Tt[w], S = Ss[w], KB = Kb[w];
        f32x4 acc = (f32x4){0.f, 0.f, 0.f, 0.f};
        #pragma unroll
        for (int kk = 0; kk < 4; ++kk) {
            bf16x8 a  = *(const bf16x8*)&Qb[(T + l15) * 136 + kk * 32 + lg * 8];
            bf16x8 bb = *(const bf16x8*)&Koff[(KB + S + l15) * 136 + kk * 32 + lg * 8];
            acc = __builtin_amdgcn_mfma_f32_16x16x32_bf16(a, bb, acc, 0, 0, 0);
        }
        #pragma unroll
        for (int r = 0; r < 4; ++r)
            At[(T + lg * 4 + r) * 72 + S + l15] = f2bf(acc[r]);
    } else if (w < 14) {    // diagonal 16x16 blocks (scalar, masked, log-space)
        const int d = (w - 6) >> 1, hf = (w - 6) & 1;
        #pragma unroll
        for (int pp = 0; pp < 2; ++pp) {
            const int p = hf * 128 + pp * 64 + lane;
            const int i_ = p >> 4, j_ = p & 15;
            if (j_ <= i_) {
                const int ti = d * 16 + i_, tj = d * 16 + j_;
                float a = 0.f;
                for (int dk = 0; dk < 128; ++dk) {
                    const float qf = bf2f(qraw[ti * 136 + dk]);
                    const float kf = bf2f(kraw[tj * 136 + dk]);
                    a += qf * kf * __expf(g[ti * 132 + dk] - g[tj * 132 + dk]);
                }
                At[ti * 72 + tj] = f2bf(a);
            }
        }
    }
    __syncthreads();

    // ---- phase 4: V^T build (overlays dead g/qraw region) ----
    {
        const int dv4 = (tid & 63) * 4, tseg = tid >> 6;
        float4 vv[4];
        #pragma unroll
        for (int s = 0; s < 4; ++s)
            vv[s] = *(const float4*)&vb[(rowbase + tseg * 4 + s) * 1024 + h * 256 + dv4];
        const float* vf = (const float*)vv;
        #pragma unroll
        for (int c = 0; c < 4; ++c) {
            int lo = (unsigned)f2bf(vf[0 * 4 + c]) | ((unsigned)f2bf(vf[1 * 4 + c]) << 16);
            int hi = (unsigned)f2bf(vf[2 * 4 + c]) | ((unsigned)f2bf(vf[3 * 4 + c]) << 16);
            *(int2*)((char*)VT + (size_t)(dv4 + c) * 144 + tseg * 8) = make_int2(lo, hi);
        }
    }
    __syncthreads();

    // ---- phase 5: PV (o intra) + state S_local (MFMA) ----
    float* sp = Sl + (((size_t)co * 16 + bh) << 15);
    for (int id = w; id < 192; id += 16) {
        if (id < 64) {
            const int mt = id >> 4, nt = id & 15;
            f32x4 acc = (f32x4){0.f, 0.f, 0.f, 0.f};
            #pragma unroll
            for (int kk = 0; kk < 2; ++kk) {
                bf16x8 a  = *(const bf16x8*)&At[(mt * 16 + l15) * 72 + kk * 32 + lg * 8];
                bf16x8 bb = *(const bf16x8*)&VT[(nt * 16 + l15) * 72 + kk * 32 + lg * 8];
                acc = __builtin_amdgcn_mfma_f32_16x16x32_bf16(a, bb, acc, 0, 0, 0);
            }
            #pragma unroll
            for (int r = 0; r < 4; ++r)
                o[(rowbase + mt * 16 + lg * 4 + r) * 1024 + h * 256 + nt * 16 + l15] = acc[r];
        } else {
            const int sid = id - 64;
            const int mt = sid >> 4, nt = sid & 15;
            f32x4 acc = (f32x4){0.f, 0.f, 0.f, 0.f};
            #pragma unroll
            for (int kk = 0; kk < 2; ++kk) {
                bf16x8 a  = *(const bf16x8*)&KhT[(mt * 16 + l15) * 72 + kk * 32 + lg * 8];
                bf16x8 bb = *(const bf16x8*)&VT[(nt * 16 + l15) * 72 + kk * 32 + lg * 8];
                acc = __builtin_amdgcn_mfma_f32_16x16x32_bf16(a, bb, acc, 0, 0, 0);
            }
            #pragma unroll
            for (int r = 0; r < 4; ++r)
                sp[(size_t)(mt * 16 + lg * 4 + r) * 256 + nt * 16 + l15] = acc[r];
        }
    }
}

// sequential chunk combine (32 chunks): overwrite Sl[c] with chunk-c START state
__global__ __launch_bounds__(256) void combine(float* __restrict__ Sl,
                                               const float* __restrict__ Dc) {
    const int bh = blockIdx.y;
    const int e4 = blockIdx.x * 256 + threadIdx.x;
    const int dk = e4 >> 6;
    float4 s = make_float4(0.f, 0.f, 0.f, 0.f);
    #pragma unroll 4
    for (int c = 0; c < NCC; ++c) {
        float4* p = (float4*)(Sl + (((size_t)c * 16 + bh) << 15)) + e4;
        float4 local = *p;
        const float d = Dc[(c * 16 + bh) * DKn + dk];
        *p = s;
        s.x = s.x * d + local.x;  s.y = s.y * d + local.y;
        s.z = s.z * d + local.z;  s.w = s.w * d + local.w;
    }
}

// inter-chunk correction: o[t][dv] += sum_dk q~[t][dk] * S_start[dk][dv]
__global__ __launch_bounds__(256, 4) void fixup(const float* __restrict__ qt,
    const float* __restrict__ Sl, float* __restrict__ o)
{
    __shared__ __align__(16) float Aq[16][68];
    __shared__ __align__(16) float Bs[16][68];
    const int raw = blockIdx.x;
    const int l = (raw & 7) * 256 + (raw >> 3);
    const int dvt = l & 3, bh = (l >> 2) & 15, co = l >> 6;
    const int b = bh >> 2, h = bh & 3;
    const int tid = threadIdx.x;
    const int tx = tid & 15, ty = tid >> 4;
    const int t0 = co * CLEN;
    const int dv0 = dvt * 64;

    const float* qbase = qt + (size_t)(b * Tn + t0) * 1024 + h * 128;
    const float* sbase = Sl + (((size_t)co * 16 + bh) << 15) + dv0;

    float acc[4][4] = {};
    for (int k0 = 0; k0 < DKn; k0 += 16) {
        __syncthreads();
        {
            const int t = tid >> 2, kk4 = (tid & 3) << 2;
            float4 a = *(const float4*)&qbase[(size_t)t * 1024 + k0 + kk4];
            Aq[kk4 + 0][t] = a.x; Aq[kk4 + 1][t] = a.y;
            Aq[kk4 + 2][t] = a.z; Aq[kk4 + 3][t] = a.w;
        }
        {
            const int dk = tid >> 4, dvq = (tid & 15) << 2;
            *(float4*)&Bs[dk][dvq] = *(const float4*)&sbase[(size_t)(k0 + dk) * 256 + dvq];
        }
        __syncthreads();
        #pragma unroll
        for (int kk = 0; kk < 16; ++kk) {
            float4 a  = *(const float4*)&Aq[kk][ty * 4];
            float4 bv = *(const float4*)&Bs[kk][tx * 4];
            float ar[4] = {a.x, a.y, a.z, a.w};
            float br[4] = {bv.x, bv.y, bv.z, bv.w};
            #pragma unroll
            for (int i = 0; i < 4; ++i)
                #pragma unroll
                for (int j = 0; j < 4; ++j)
                    acc[i][j] += ar[i] * br[j];
        }
    }
    float* obp = o + (size_t)(b * Tn + t0) * 1024 + h * 256 + dv0;
    #pragma unroll
    for (int i = 0; i < 4; ++i) {
        float* row = obp + (size_t)(ty * 4 + i) * 1024 + tx * 4;
        float4 c = *(float4*)row;
        c.x += acc[i][0]; c.y += acc[i][1];
        c.z += acc[i][2]; c.w += acc[i][3];
        *(float4*)row = c;
    }
}

// ---------- RMSNorm + swish gate (g in bf16) -> bf16 ----------
__global__ __launch_bounds__(256) void rms_gate(const float* __restrict__ o,
    const ushort* __restrict__ gbf, const float* __restrict__ wt,
    ushort* __restrict__ obf)
{
    const int tid = threadIdx.x;
    const int w = tid >> 6, lane = tid & 63;
    const int row = blockIdx.x * 4 + w;
    const int n = row >> 2, h = row & 3;
    const size_t ob_base = (size_t)n * VDn + h * DVn + lane * 4;

    float4 o4 = *(const float4*)&o[ob_base];
    float ss = o4.x*o4.x + o4.y*o4.y + o4.z*o4.z + o4.w*o4.w;
    #pragma unroll
    for (int m = 1; m < 64; m <<= 1) ss += __shfl_xor(ss, m);
    const float r = rsqrtf(ss * (1.0f / DVn) + 1e-5f);

    ushort4 gu = *(const ushort4*)&gbf[ob_base];
    float gx = bf2f(gu.x), gy = bf2f(gu.y), gz = bf2f(gu.z), gw = bf2f(gu.w);
    float4 w4 = *(const float4*)&wt[h * DVn + lane * 4];
    ushort4 u;
    u.x = f2bf(o4.x * r * w4.x * (gx / (1.0f + expf(-gx))));
    u.y = f2bf(o4.y * r * w4.y * (gy / (1.0f + expf(-gy))));
    u.z = f2bf(o4.z * r * w4.z * (gz / (1.0f + expf(-gz))));
    u.w = f2bf(o4.w * r * w4.w * (gw / (1.0f + expf(-gw))));
    *(ushort4*)&obf[ob_base] = u;
}

extern "C" void kernel_launch(void* const* d_in, const int* in_sizes, int n_in,
                              void* d_out, int out_size, void* d_ws, size_t ws_size,
                              hipStream_t stream) {
    const float* hs          = (const float*)d_in[0];
    const float* Wq          = (const float*)d_in[1];
    const float* Wk          = (const float*)d_in[2];
    const float* Wv          = (const float*)d_in[3];
    const float* Wg          = (const float*)d_in[4];
    const float* Wa          = (const float*)d_in[5];
    const float* Wo          = (const float*)d_in[6];
    const float* A_log_base  = (const float*)d_in[7];
    const float* A_log_delta = (const float*)d_in[8];
    const float* dt_bias     = (const float*)d_in[9];
    const float* gnw         = (const float*)d_in[10];
    float* out = (float*)d_out;

    char* ws = (char*)d_ws;
    float*  qk   = (float*)(ws);                           // 32MB [8192][1024] q|k (q~ in place)
    float*  vb   = (float*)(ws + ((size_t)32  << 20));     // 32MB [8192][1024] v
    float*  Gbuf = (float*)(ws + ((size_t)64  << 20));     // 16MB [8192][512] log-decay
    float*  Sl   = (float*)(ws + ((size_t)80  << 20));     // 64MB [32][16][128][256]
    float*  ob   = (float*)(ws + ((size_t)144 << 20));     // 32MB [8192][1024]
    ushort* hsb  = (ushort*)(ws + ((size_t)144 << 20));    // 16MB overlay on ob
    ushort* gbf  = (ushort*)(ws + ((size_t)176 << 20));    // 16MB [8192][1024] g bf16
    ushort* Wcat = (ushort*)(ws + ((size_t)192 << 20));    //  7MB [3584][1024] q|k|a|v|g
    ushort* Wob  = (ushort*)(ws + ((size_t)199 << 20));    //  2MB
    float*  Dc   = (float*)(ws + ((size_t)201 << 20));     // 256KB [32*16][128]
    ushort* obf  = (ushort*)qk;                            // reuse qk after fixup

    // fused casts (weights concatenated q|k|a|v|g)
    CastArgs ca;
    ca.src[0] = hs; ca.src[1] = Wq; ca.src[2] = Wk; ca.src[3] = Wa;
    ca.src[4] = Wv; ca.src[5] = Wg; ca.src[6] = Wo;
    ca.dst[0] = hsb;
    ca.dst[1] = Wcat;
    ca.dst[2] = Wcat + (size_t)512 * 1024;
    ca.dst[3] = Wcat + (size_t)1024 * 1024;
    ca.dst[4] = Wcat + (size_t)1536 * 1024;
    ca.dst[5] = Wcat + (size_t)2560 * 1024;
    ca.dst[6] = Wob;
    const int n4s[7] = {NROWS * Dn / 4, KDn * Dn / 4, KDn * Dn / 4, KDn * Dn / 4,
                        VDn * Dn / 4, VDn * Dn / 4, VDn * Dn / 4};
    ca.cum[0] = 0;
    for (int i = 0; i < 7; ++i) ca.cum[i + 1] = ca.cum[i] + n4s[i];
    cast_all<<<2048, 256, 0, stream>>>(ca);

    // fused projection GEMM: q|k -> qk, a -> Gbuf (log decay), v -> vb, g -> gbf
    mm3<1,28><<<1792, 256, 0, stream>>>(hsb, Wcat, qk, vb, gbf, Gbuf,
                                        dt_bias, A_log_base, A_log_delta);

    // chunked recurrence: log-space attention form
    (void)hipFuncSetAttribute((const void*)gla_chunk,
                              hipFuncAttributeMaxDynamicSharedMemorySize, 139776);
    gla_chunk<<<512, 1024, 139776, stream>>>(qk, Gbuf, vb, ob, Sl, Dc);
    combine<<<dim3(32, 16), 256, 0, stream>>>(Sl, Dc);
    fixup<<<2048, 256, 0, stream>>>(qk, Sl, ob);

    // epilogue
    rms_gate<<<NROWS * Hn / 4, 256, 0, stream>>>(ob, gbf, gnw, obf);
    mm3<0,8><<<512, 256, 0, stream>>>(obf, Wob, out, nullptr, nullptr, nullptr,
                                      nullptr, nullptr, nullptr);
}